// Round 1
// baseline (2739.269 us; speedup 1.0000x reference)
//
#include <hip/hip_runtime.h>
#include <math.h>

#define BB 8
#define SS 1024
#define DD 512
#define HH 8
#define DK 64
#define FF 2048
#define NCLS 10
#define ROWS (BB*SS)   // 8192
#define NLAYERS 2

// ---------------- embedding + sinusoidal positional encoding ----------------
__global__ __launch_bounds__(128) void k_embed_pe(const int* __restrict__ tokens,
                                                  const float* __restrict__ emb,
                                                  float* __restrict__ x) {
    int row = blockIdx.x;            // b*S + s
    int s = row & (SS - 1);
    int tok = tokens[row];
    const float4* e = reinterpret_cast<const float4*>(emb + (size_t)tok * DD);
    float4 v = e[threadIdx.x];
    float pe[4];
#pragma unroll
    for (int j = 0; j < 4; ++j) {
        int d = threadIdx.x * 4 + j;
        int jj = d >> 1;
        // 10000^(-(2jj)/D) = exp(-(2jj/D)*ln(10000))
        float inv = expf(-((float)(2 * jj) / (float)DD) * 9.210340371976184f);
        float ang = (float)s * inv;
        pe[j] = (d & 1) ? cosf(ang) : sinf(ang);
    }
    v.x += pe[0]; v.y += pe[1]; v.z += pe[2]; v.w += pe[3];
    reinterpret_cast<float4*>(x + (size_t)row * DD)[threadIdx.x] = v;
}

// ---------------- p = cos(x + theta) (theta broadcast over rows) ----------------
__global__ __launch_bounds__(256) void k_cosproj(const float* __restrict__ x,
                                                 const float* __restrict__ theta,
                                                 float* __restrict__ p, int n4) {
    int i = blockIdx.x * 256 + threadIdx.x;
    if (i >= n4) return;
    float4 xv = reinterpret_cast<const float4*>(x)[i];
    int d4 = i & (DD / 4 - 1);
    float4 tv = reinterpret_cast<const float4*>(theta)[d4];
    float4 r;
    r.x = cosf(xv.x + tv.x);
    r.y = cosf(xv.y + tv.y);
    r.z = cosf(xv.z + tv.z);
    r.w = cosf(xv.w + tv.w);
    reinterpret_cast<float4*>(p)[i] = r;
}

// ---------------- attention: q=k=v=p, per-thread one q row, streaming softmax ----
// |score| <= 64 * 0.125 = 8  =>  no max subtraction needed (exp <= e^8).
#define KTILE 128
__global__ __launch_bounds__(256) void k_attn(const float* __restrict__ p,
                                              float* __restrict__ out) {
    // grid: B*H*(S/256) = 256 blocks of 256 threads; one thread = one q row
    int blk = blockIdx.x;
    int qc = blk & 3;
    int h = (blk >> 2) & 7;
    int b = blk >> 5;
    int q = qc * 256 + threadIdx.x;
    const float* pb = p + (size_t)b * SS * DD + h * DK;

    float qr[DK];
#pragma unroll
    for (int j4 = 0; j4 < DK / 4; ++j4) {
        float4 v = *reinterpret_cast<const float4*>(pb + (size_t)q * DD + j4 * 4);
        qr[j4 * 4 + 0] = v.x; qr[j4 * 4 + 1] = v.y;
        qr[j4 * 4 + 2] = v.z; qr[j4 * 4 + 3] = v.w;
    }
    float acc[DK];
#pragma unroll
    for (int j = 0; j < DK; ++j) acc[j] = 0.f;
    float l = 0.f;

    __shared__ float ks[KTILE * DK];   // 32 KB

    for (int k0 = 0; k0 < SS; k0 += KTILE) {
        __syncthreads();
#pragma unroll
        for (int i = 0; i < (KTILE * DK / 4) / 256; ++i) {   // 8 float4 per thread
            int idx = threadIdx.x + i * 256;
            int r = idx >> 4;          // row in tile
            int c = idx & 15;          // float4 within row
            float4 v = *reinterpret_cast<const float4*>(pb + (size_t)(k0 + r) * DD + c * 4);
            *reinterpret_cast<float4*>(ks + r * DK + c * 4) = v;
        }
        __syncthreads();

        for (int kk = 0; kk < KTILE; ++kk) {
            const float* kr = ks + kk * DK;
            float s[8];
#pragma unroll
            for (int u = 0; u < 8; ++u) s[u] = 0.f;
#pragma unroll
            for (int j4 = 0; j4 < 16; ++j4) {
                float4 kv = *reinterpret_cast<const float4*>(kr + j4 * 4);
                int u = (j4 & 1) * 4;
                s[u + 0] += qr[j4 * 4 + 0] * kv.x;
                s[u + 1] += qr[j4 * 4 + 1] * kv.y;
                s[u + 2] += qr[j4 * 4 + 2] * kv.z;
                s[u + 3] += qr[j4 * 4 + 3] * kv.w;
            }
            float sc = ((s[0] + s[1]) + (s[2] + s[3])) + ((s[4] + s[5]) + (s[6] + s[7]));
            float w = __expf(sc * 0.125f);
            l += w;
#pragma unroll
            for (int j4 = 0; j4 < 16; ++j4) {
                float4 kv = *reinterpret_cast<const float4*>(kr + j4 * 4);
                acc[j4 * 4 + 0] += w * kv.x;
                acc[j4 * 4 + 1] += w * kv.y;
                acc[j4 * 4 + 2] += w * kv.z;
                acc[j4 * 4 + 3] += w * kv.w;
            }
        }
    }
    float inv = 1.0f / l;
    float* op = out + ((size_t)b * SS + q) * DD + h * DK;
#pragma unroll
    for (int j4 = 0; j4 < DK / 4; ++j4) {
        float4 v;
        v.x = acc[j4 * 4 + 0] * inv; v.y = acc[j4 * 4 + 1] * inv;
        v.z = acc[j4 * 4 + 2] * inv; v.w = acc[j4 * 4 + 3] * inv;
        *reinterpret_cast<float4*>(op + j4 * 4) = v;
    }
}

// ---------------- fp32 GEMM: C = A[M,K] @ B[K,N] + bias, optional relu ----------
// 128x128 tile, BK=16, 256 threads, 8x8 micro-tile (cols split tx*4 and 64+tx*4)
template <int RELU>
__global__ __launch_bounds__(256) void k_gemm(const float* __restrict__ A,
                                              const float* __restrict__ Bw,
                                              const float* __restrict__ bias,
                                              float* __restrict__ C,
                                              int M, int N, int K) {
    __shared__ float As[16][128];
    __shared__ float Bs[16][128];
    const int tid = threadIdx.x;
    const int row0 = blockIdx.y * 128;
    const int col0 = blockIdx.x * 128;
    const int tx = tid & 15;
    const int ty = tid >> 4;

    float acc[8][8];
#pragma unroll
    for (int i = 0; i < 8; ++i)
#pragma unroll
        for (int j = 0; j < 8; ++j) acc[i][j] = 0.f;

    const int ar = tid >> 2;
    const int ac = (tid & 3) * 4;
    const int br = tid >> 5;
    const int bcc = (tid & 31) * 4;

    for (int k0 = 0; k0 < K; k0 += 16) {
#pragma unroll
        for (int i = 0; i < 2; ++i) {
            int r = ar + i * 64;
            float4 v = *reinterpret_cast<const float4*>(A + (size_t)(row0 + r) * K + k0 + ac);
            As[ac + 0][r] = v.x; As[ac + 1][r] = v.y;
            As[ac + 2][r] = v.z; As[ac + 3][r] = v.w;
        }
#pragma unroll
        for (int i = 0; i < 2; ++i) {
            int r = br + i * 8;
            float4 v = *reinterpret_cast<const float4*>(Bw + (size_t)(k0 + r) * N + col0 + bcc);
            *reinterpret_cast<float4*>(&Bs[r][bcc]) = v;
        }
        __syncthreads();
#pragma unroll
        for (int kk = 0; kk < 16; ++kk) {
            float a[8], b[8];
            *reinterpret_cast<float4*>(&a[0]) = *reinterpret_cast<const float4*>(&As[kk][ty * 8]);
            *reinterpret_cast<float4*>(&a[4]) = *reinterpret_cast<const float4*>(&As[kk][ty * 8 + 4]);
            *reinterpret_cast<float4*>(&b[0]) = *reinterpret_cast<const float4*>(&Bs[kk][tx * 4]);
            *reinterpret_cast<float4*>(&b[4]) = *reinterpret_cast<const float4*>(&Bs[kk][64 + tx * 4]);
#pragma unroll
            for (int i = 0; i < 8; ++i)
#pragma unroll
                for (int j = 0; j < 8; ++j) acc[i][j] += a[i] * b[j];
        }
        __syncthreads();
    }

    float4 bv0 = *reinterpret_cast<const float4*>(bias + col0 + tx * 4);
    float4 bv1 = *reinterpret_cast<const float4*>(bias + col0 + 64 + tx * 4);
#pragma unroll
    for (int i = 0; i < 8; ++i) {
        int r = row0 + ty * 8 + i;
        float o0[4] = {acc[i][0] + bv0.x, acc[i][1] + bv0.y, acc[i][2] + bv0.z, acc[i][3] + bv0.w};
        float o1[4] = {acc[i][4] + bv1.x, acc[i][5] + bv1.y, acc[i][6] + bv1.z, acc[i][7] + bv1.w};
        if (RELU) {
#pragma unroll
            for (int j = 0; j < 4; ++j) { o0[j] = fmaxf(o0[j], 0.f); o1[j] = fmaxf(o1[j], 0.f); }
        }
        *reinterpret_cast<float4*>(C + (size_t)r * N + col0 + tx * 4) = *reinterpret_cast<float4*>(o0);
        *reinterpret_cast<float4*>(C + (size_t)r * N + col0 + 64 + tx * 4) = *reinterpret_cast<float4*>(o1);
    }
}

// ---------------- x = LayerNorm(x + r) * g + b ----------------
__global__ __launch_bounds__(128) void k_add_ln(float* __restrict__ x,
                                                const float* __restrict__ rr,
                                                const float* __restrict__ g,
                                                const float* __restrict__ bb) {
    int row = blockIdx.x;
    int t = threadIdx.x;   // 128 threads x 4 elems
    float4 v = *reinterpret_cast<const float4*>(x + (size_t)row * DD + t * 4);
    float4 av = *reinterpret_cast<const float4*>(rr + (size_t)row * DD + t * 4);
    v.x += av.x; v.y += av.y; v.z += av.z; v.w += av.w;
    float s = v.x + v.y + v.z + v.w;
    float s2 = v.x * v.x + v.y * v.y + v.z * v.z + v.w * v.w;
#pragma unroll
    for (int off = 32; off > 0; off >>= 1) {
        s += __shfl_down(s, off);
        s2 += __shfl_down(s2, off);
    }
    __shared__ float ls[2], ls2[2];
    if ((t & 63) == 0) { ls[t >> 6] = s; ls2[t >> 6] = s2; }
    __syncthreads();
    float S1 = ls[0] + ls[1];
    float S2 = ls2[0] + ls2[1];
    float mu = S1 * (1.0f / DD);
    float var = S2 * (1.0f / DD) - mu * mu;
    float rstd = rsqrtf(var + 1e-5f);
    float4 gv = *reinterpret_cast<const float4*>(g + t * 4);
    float4 bv = *reinterpret_cast<const float4*>(bb + t * 4);
    float4 o;
    o.x = gv.x * (v.x - mu) * rstd + bv.x;
    o.y = gv.y * (v.y - mu) * rstd + bv.y;
    o.z = gv.z * (v.z - mu) * rstd + bv.z;
    o.w = gv.w * (v.w - mu) * rstd + bv.w;
    *reinterpret_cast<float4*>(x + (size_t)row * DD + t * 4) = o;
}

// ---------------- mean-pool over S + classifier ----------------
__global__ __launch_bounds__(512) void k_head(const float* __restrict__ x,
                                              const float* __restrict__ Wcls,
                                              const float* __restrict__ bcls,
                                              float* __restrict__ out) {
    int b = blockIdx.x;
    int d = threadIdx.x;
    float s = 0.f;
    for (int si = 0; si < SS; ++si) s += x[((size_t)b * SS + si) * DD + d];
    __shared__ float pooled[DD];
    pooled[d] = s * (1.0f / SS);
    __syncthreads();
    if (d < NCLS) {
        float acc = bcls[d];
        for (int j = 0; j < DD; ++j) acc += pooled[j] * Wcls[j * NCLS + d];
        out[b * NCLS + d] = acc;
    }
}

extern "C" void kernel_launch(void* const* d_in, const int* in_sizes, int n_in,
                              void* d_out, int out_size, void* d_ws, size_t ws_size,
                              hipStream_t stream) {
    const int* tokens      = (const int*)d_in[0];
    const float* emb       = (const float*)d_in[1];
    const float* theta_att = (const float*)d_in[2];
    const float* Wc        = (const float*)d_in[3];
    const float* bc        = (const float*)d_in[4];
    const float* ln1_g     = (const float*)d_in[5];
    const float* ln1_b     = (const float*)d_in[6];
    const float* theta_ffn = (const float*)d_in[7];
    const float* W1        = (const float*)d_in[8];
    const float* b1        = (const float*)d_in[9];
    const float* W2        = (const float*)d_in[10];
    const float* b2        = (const float*)d_in[11];
    const float* ln2_g     = (const float*)d_in[12];
    const float* ln2_b     = (const float*)d_in[13];
    const float* Wcls      = (const float*)d_in[14];
    const float* bcls      = (const float*)d_in[15];
    float* out = (float*)d_out;

    float* ws = (float*)d_ws;
    float* x  = ws;                          // 4M floats (16 MB)
    float* p  = ws + (size_t)4 * 1024 * 1024;   // 16 MB
    float* a  = ws + (size_t)8 * 1024 * 1024;   // 16 MB
    float* hh = ws + (size_t)12 * 1024 * 1024;  // 64 MB
    // total 112 MB

    const int n4 = ROWS * DD / 4;   // 1,048,576

    k_embed_pe<<<ROWS, 128, 0, stream>>>(tokens, emb, x);

    for (int l = 0; l < NLAYERS; ++l) {
        // --- MHA ---
        k_cosproj<<<n4 / 256, 256, 0, stream>>>(x, theta_att + l * DD, p, n4);
        k_attn<<<BB * HH * (SS / 256), 256, 0, stream>>>(p, a);
        k_gemm<0><<<dim3(DD / 128, ROWS / 128), 256, 0, stream>>>(
            a, Wc + (size_t)l * DD * DD, bc + l * DD, p, ROWS, DD, DD);
        k_add_ln<<<ROWS, 128, 0, stream>>>(x, p, ln1_g + l * DD, ln1_b + l * DD);
        // --- FFN ---
        k_cosproj<<<n4 / 256, 256, 0, stream>>>(x, theta_ffn + l * DD, p, n4);
        k_gemm<1><<<dim3(FF / 128, ROWS / 128), 256, 0, stream>>>(
            p, W1 + (size_t)l * DD * FF, b1 + l * FF, hh, ROWS, FF, DD);
        k_gemm<0><<<dim3(DD / 128, ROWS / 128), 256, 0, stream>>>(
            hh, W2 + (size_t)l * FF * DD, b2 + l * DD, p, ROWS, DD, FF);
        k_add_ln<<<ROWS, 128, 0, stream>>>(x, p, ln2_g + l * DD, ln2_b + l * DD);
    }

    k_head<<<BB, 512, 0, stream>>>(x, Wcls, bcls, out);
}

// Round 2
// 536.438 us; speedup vs baseline: 5.1064x; 5.1064x over previous
//
#include <hip/hip_runtime.h>
#include <math.h>

#define BB 8
#define SS 1024
#define DD 512
#define HH 8
#define DK 64
#define FF 2048
#define NCLS 10
#define ROWS (BB*SS)   // 8192
#define NLAYERS 2

typedef short bf16x8 __attribute__((ext_vector_type(8)));
typedef float f32x4 __attribute__((ext_vector_type(4)));

__device__ inline short f2bf(float f) {
    unsigned u = __float_as_uint(f);
    u += 0x7FFF + ((u >> 16) & 1);          // round-to-nearest-even
    return (short)(u >> 16);
}

__device__ inline void gload_lds16(const void* g, void* l) {
    __builtin_amdgcn_global_load_lds((const __attribute__((address_space(1))) void*)g,
                                     (__attribute__((address_space(3))) void*)l, 16, 0, 0);
}

// ---------------- embedding + sinusoidal positional encoding ----------------
__global__ __launch_bounds__(128) void k_embed_pe(const int* __restrict__ tokens,
                                                  const float* __restrict__ emb,
                                                  float* __restrict__ x) {
    int row = blockIdx.x;            // b*S + s
    int s = row & (SS - 1);
    int tok = tokens[row];
    const float4* e = reinterpret_cast<const float4*>(emb + (size_t)tok * DD);
    float4 v = e[threadIdx.x];
    float pe[4];
#pragma unroll
    for (int j = 0; j < 4; ++j) {
        int d = threadIdx.x * 4 + j;
        int jj = d >> 1;
        float inv = expf(-((float)(2 * jj) / (float)DD) * 9.210340371976184f);
        float ang = (float)s * inv;
        pe[j] = (d & 1) ? cosf(ang) : sinf(ang);
    }
    v.x += pe[0]; v.y += pe[1]; v.z += pe[2]; v.w += pe[3];
    reinterpret_cast<float4*>(x + (size_t)row * DD)[threadIdx.x] = v;
}

// ---------------- fused cos-projection -> bf16 p, optionally transposed p_t ----
// tile: 64 s-rows x 64 d-cols per (b). grid (8 dtiles, 16 stiles, 8 b), 256 thr.
template <int WT>
__global__ __launch_bounds__(256) void k_cosp(const float* __restrict__ x,
                                              const float* __restrict__ theta,
                                              short* __restrict__ p,
                                              short* __restrict__ pt) {
    int d0 = blockIdx.x * 64, s0 = blockIdx.y * 64, b = blockIdx.z;
    int t = threadIdx.x;
    int tc = t & 15, tr = t >> 4;
    __shared__ short lt[64][68];
    float4 th = *reinterpret_cast<const float4*>(theta + d0 + tc * 4);
#pragma unroll
    for (int i = 0; i < 4; ++i) {
        int s = tr + 16 * i;
        float4 xv = *reinterpret_cast<const float4*>(
            x + ((size_t)b * SS + s0 + s) * DD + d0 + tc * 4);
        short4 o;
        o.x = f2bf(cosf(xv.x + th.x));
        o.y = f2bf(cosf(xv.y + th.y));
        o.z = f2bf(cosf(xv.z + th.z));
        o.w = f2bf(cosf(xv.w + th.w));
        *reinterpret_cast<short4*>(p + ((size_t)b * SS + s0 + s) * DD + d0 + tc * 4) = o;
        if (WT) {
            lt[tc * 4 + 0][s] = o.x;
            lt[tc * 4 + 1][s] = o.y;
            lt[tc * 4 + 2][s] = o.z;
            lt[tc * 4 + 3][s] = o.w;
        }
    }
    if (WT) {
        __syncthreads();
#pragma unroll
        for (int i = 0; i < 4; ++i) {
            int d = tr + 16 * i;
            short4 v;
            v.x = lt[d][tc * 4 + 0];
            v.y = lt[d][tc * 4 + 1];
            v.z = lt[d][tc * 4 + 2];
            v.w = lt[d][tc * 4 + 3];
            *reinterpret_cast<short4*>(pt + ((size_t)b * DD + d0 + d) * SS + s0 + tc * 4) = v;
        }
    }
}

// ---------------- weight transpose+convert: f32 [K][N] -> bf16 [N][K] ----------
__global__ __launch_bounds__(256) void k_wtrans(const float* __restrict__ W,
                                                short* __restrict__ Wt,
                                                int K, int N) {
    __shared__ float tile[32][33];
    int n0 = blockIdx.x * 32, k0 = blockIdx.y * 32;
    int tx = threadIdx.x & 31, ty = threadIdx.x >> 5;   // 32 x 8
#pragma unroll
    for (int i = 0; i < 4; ++i)
        tile[ty + 8 * i][tx] = W[(size_t)(k0 + ty + 8 * i) * N + n0 + tx];
    __syncthreads();
#pragma unroll
    for (int i = 0; i < 4; ++i)
        Wt[(size_t)(n0 + ty + 8 * i) * K + k0 + tx] = f2bf(tile[tx][ty + 8 * i]);
}

// ---------------- MFMA attention (q=k=v=p), streaming softmax, no max needed ---
// |score| <= 8 -> exp(score) in [3e-4, 3e3]: plain running sum, divide at end.
// Orientation: S^T = K*Q^T  (C-frag: col=lane&15=q, row=k-subindex) so each lane
// holds P for ONE q row.  PV as O^T = V^T * P^T (V^T staged from pre-transposed pt).
__global__ __launch_bounds__(256) void k_attn(const short* __restrict__ p,
                                              const short* __restrict__ pt,
                                              short* __restrict__ aout) {
    int qc = blockIdx.x, h = blockIdx.y, b = blockIdx.z;
    int t = threadIdx.x, w = t >> 6, l = t & 63;
    int lg = l >> 4, lr = l & 15;

    __shared__ __attribute__((aligned(16))) short Kt[128 * 64];   // [k][d] 16KB
    __shared__ __attribute__((aligned(16))) short Vt[64 * 128];   // [d][k] 16KB
    __shared__ __attribute__((aligned(16))) short Pl[4][16 * 136]; // per-wave P [q][k]

    // Q B-frags (fixed): lane reads Q[q = qbase+lr, d-slice]
    const size_t prow = ((size_t)b * SS + qc * 64 + w * 16 + lr) * DD + h * DK;
    bf16x8 qf0 = *reinterpret_cast<const bf16x8*>(p + prow + lg * 8);
    bf16x8 qf1 = *reinterpret_cast<const bf16x8*>(p + prow + 32 + lg * 8);

    f32x4 acc[4];
#pragma unroll
    for (int dt = 0; dt < 4; ++dt) acc[dt] = (f32x4){0.f, 0.f, 0.f, 0.f};
    float denom = 0.f;

    const short* pK = p + (size_t)b * SS * DD + h * DK;        // + k*DD
    const short* pV = pt + ((size_t)b * DD + h * DK) * SS;     // + d*SS

    short* myP = &Pl[w][0];

    for (int k0 = 0; k0 < SS; k0 += 128) {
        __syncthreads();
        // stage K-tile [128][64], swizzle slot^ (row&7)
#pragma unroll
        for (int i = 0; i < 4; ++i) {
            int c = i * 256 + t;
            int row = c >> 3, sl = c & 7, ssl = sl ^ (row & 7);
            gload_lds16(pK + (size_t)(k0 + row) * DD + ssl * 8,
                        Kt + (size_t)(i * 256 + w * 64) * 8);
        }
        // stage V^T-tile [64][128], swizzle slot ^ (2*(row&7))
#pragma unroll
        for (int i = 0; i < 4; ++i) {
            int c = i * 256 + t;
            int row = c >> 4, sl = c & 15, ssl = sl ^ ((row & 7) * 2);
            gload_lds16(pV + (size_t)row * SS + k0 + ssl * 8,
                        Vt + (size_t)(i * 256 + w * 64) * 8);
        }
        asm volatile("s_waitcnt vmcnt(0)" ::: "memory");
        __syncthreads();

        // QK^T: S^T[k,q] per 16-k subtile
        f32x4 sc[8];
#pragma unroll
        for (int kt = 0; kt < 8; ++kt) {
            int row = kt * 16 + lr;
            bf16x8 ka0 = *reinterpret_cast<const bf16x8*>(Kt + row * 64 + ((lg ^ (row & 7)) * 8));
            bf16x8 ka1 = *reinterpret_cast<const bf16x8*>(Kt + row * 64 + (((lg + 4) ^ (row & 7)) * 8));
            f32x4 z = (f32x4){0.f, 0.f, 0.f, 0.f};
            z = __builtin_amdgcn_mfma_f32_16x16x32_bf16(ka0, qf0, z, 0, 0, 0);
            z = __builtin_amdgcn_mfma_f32_16x16x32_bf16(ka1, qf1, z, 0, 0, 0);
            sc[kt] = z;
        }
        // exp (no max subtraction), accumulate denom, pack to per-wave P LDS
#pragma unroll
        for (int kt = 0; kt < 8; ++kt) {
            float e0 = __expf(sc[kt].x * 0.125f);
            float e1 = __expf(sc[kt].y * 0.125f);
            float e2 = __expf(sc[kt].z * 0.125f);
            float e3 = __expf(sc[kt].w * 0.125f);
            denom += (e0 + e1) + (e2 + e3);
            short4 pk;
            pk.x = f2bf(e0); pk.y = f2bf(e1); pk.z = f2bf(e2); pk.w = f2bf(e3);
            *reinterpret_cast<short4*>(myP + lr * 136 + kt * 16 + lg * 4) = pk;
        }
        asm volatile("s_waitcnt lgkmcnt(0)" ::: "memory");
        // PV: O^T[d,q] += V^T[d,k32] * P^T[k32,q]
#pragma unroll
        for (int kt2 = 0; kt2 < 4; ++kt2) {
            bf16x8 pb = *reinterpret_cast<const bf16x8*>(myP + lr * 136 + kt2 * 32 + lg * 8);
#pragma unroll
            for (int dt = 0; dt < 4; ++dt) {
                int row = dt * 16 + lr;
                bf16x8 va = *reinterpret_cast<const bf16x8*>(
                    Vt + row * 128 + (((kt2 * 4 + lg) ^ ((row & 7) * 2)) * 8));
                acc[dt] = __builtin_amdgcn_mfma_f32_16x16x32_bf16(va, pb, acc[dt], 0, 0, 0);
            }
        }
    }

    denom += __shfl_xor(denom, 16);
    denom += __shfl_xor(denom, 32);
    float inv = 1.0f / denom;

    // O^T C-frag: col=lr=q, row = lg*4+j = d-within-16
    size_t orow = ((size_t)b * SS + qc * 64 + w * 16 + lr) * DD + h * DK;
#pragma unroll
    for (int dt = 0; dt < 4; ++dt) {
        short4 o;
        o.x = f2bf(acc[dt].x * inv);
        o.y = f2bf(acc[dt].y * inv);
        o.z = f2bf(acc[dt].z * inv);
        o.w = f2bf(acc[dt].w * inv);
        *reinterpret_cast<short4*>(aout + orow + dt * 16 + lg * 4) = o;
    }
}

// ---------------- bf16 MFMA GEMM: C[M,N] = A[M,K] * W[K,N] + bias ---------------
// A bf16 row-major, Bt = W^T bf16 [N][K].  128x128 tile, BK=32, 4 waves (2x2).
template <int RELU, int OUTBF>
__global__ __launch_bounds__(256) void k_mm(const short* __restrict__ A,
                                            const short* __restrict__ Bt,
                                            const float* __restrict__ bias,
                                            void* __restrict__ C,
                                            int N, int K) {
    __shared__ __attribute__((aligned(16))) short Al[128 * 32];
    __shared__ __attribute__((aligned(16))) short Bl[128 * 32];
    int t = threadIdx.x, w = t >> 6, l = t & 63;
    int lg = l >> 4, lr = l & 15;
    int wm = w >> 1, wn = w & 1;
    int row0 = blockIdx.y * 128, col0 = blockIdx.x * 128;

    f32x4 acc[4][4];
#pragma unroll
    for (int m = 0; m < 4; ++m)
#pragma unroll
        for (int n = 0; n < 4; ++n) acc[m][n] = (f32x4){0.f, 0.f, 0.f, 0.f};

    for (int k0 = 0; k0 < K; k0 += 32) {
        __syncthreads();
#pragma unroll
        for (int i = 0; i < 2; ++i) {
            int c = i * 256 + t;
            int row = c >> 2, sl = c & 3, ssl = sl ^ ((row >> 1) & 3);
            gload_lds16(A + (size_t)(row0 + row) * K + k0 + ssl * 8,
                        Al + (size_t)(i * 256 + w * 64) * 8);
            gload_lds16(Bt + (size_t)(col0 + row) * K + k0 + ssl * 8,
                        Bl + (size_t)(i * 256 + w * 64) * 8);
        }
        asm volatile("s_waitcnt vmcnt(0)" ::: "memory");
        __syncthreads();

        bf16x8 af[4], bfr[4];
#pragma unroll
        for (int m = 0; m < 4; ++m) {
            int row = wm * 64 + m * 16 + lr;
            af[m] = *reinterpret_cast<const bf16x8*>(Al + row * 32 + ((lg ^ ((row >> 1) & 3)) * 8));
        }
#pragma unroll
        for (int n = 0; n < 4; ++n) {
            int row = wn * 64 + n * 16 + lr;
            bfr[n] = *reinterpret_cast<const bf16x8*>(Bl + row * 32 + ((lg ^ ((row >> 1) & 3)) * 8));
        }
#pragma unroll
        for (int m = 0; m < 4; ++m)
#pragma unroll
            for (int n = 0; n < 4; ++n)
                acc[m][n] = __builtin_amdgcn_mfma_f32_16x16x32_bf16(af[m], bfr[n], acc[m][n], 0, 0, 0);
    }

    float bv[4];
#pragma unroll
    for (int n = 0; n < 4; ++n) bv[n] = bias[col0 + wn * 64 + n * 16 + lr];

#pragma unroll
    for (int m = 0; m < 4; ++m) {
#pragma unroll
        for (int n = 0; n < 4; ++n) {
            int col = col0 + wn * 64 + n * 16 + lr;
#pragma unroll
            for (int j = 0; j < 4; ++j) {
                int row = row0 + wm * 64 + m * 16 + lg * 4 + j;
                float v = acc[m][n][j] + bv[n];
                if (RELU) v = fmaxf(v, 0.f);
                if (OUTBF) ((short*)C)[(size_t)row * N + col] = f2bf(v);
                else       ((float*)C)[(size_t)row * N + col] = v;
            }
        }
    }
}

// ---------------- x = LayerNorm(x + r) * g + b (fp32) ----------------
__global__ __launch_bounds__(128) void k_add_ln(float* __restrict__ x,
                                                const float* __restrict__ rr,
                                                const float* __restrict__ g,
                                                const float* __restrict__ bb) {
    int row = blockIdx.x;
    int t = threadIdx.x;
    float4 v = *reinterpret_cast<const float4*>(x + (size_t)row * DD + t * 4);
    float4 av = *reinterpret_cast<const float4*>(rr + (size_t)row * DD + t * 4);
    v.x += av.x; v.y += av.y; v.z += av.z; v.w += av.w;
    float s = v.x + v.y + v.z + v.w;
    float s2 = v.x * v.x + v.y * v.y + v.z * v.z + v.w * v.w;
#pragma unroll
    for (int off = 32; off > 0; off >>= 1) {
        s += __shfl_down(s, off);
        s2 += __shfl_down(s2, off);
    }
    __shared__ float ls[2], ls2[2];
    if ((t & 63) == 0) { ls[t >> 6] = s; ls2[t >> 6] = s2; }
    __syncthreads();
    float S1 = ls[0] + ls[1];
    float S2 = ls2[0] + ls2[1];
    float mu = S1 * (1.0f / DD);
    float var = S2 * (1.0f / DD) - mu * mu;
    float rstd = rsqrtf(var + 1e-5f);
    float4 gv = *reinterpret_cast<const float4*>(g + t * 4);
    float4 bv = *reinterpret_cast<const float4*>(bb + t * 4);
    float4 o;
    o.x = gv.x * (v.x - mu) * rstd + bv.x;
    o.y = gv.y * (v.y - mu) * rstd + bv.y;
    o.z = gv.z * (v.z - mu) * rstd + bv.z;
    o.w = gv.w * (v.w - mu) * rstd + bv.w;
    *reinterpret_cast<float4*>(x + (size_t)row * DD + t * 4) = o;
}

// ---------------- mean-pool over S + classifier ----------------
__global__ __launch_bounds__(512) void k_head(const float* __restrict__ x,
                                              const float* __restrict__ Wcls,
                                              const float* __restrict__ bcls,
                                              float* __restrict__ out) {
    int b = blockIdx.x;
    int d = threadIdx.x;
    float s = 0.f;
    for (int si = 0; si < SS; ++si) s += x[((size_t)b * SS + si) * DD + d];
    __shared__ float pooled[DD];
    pooled[d] = s * (1.0f / SS);
    __syncthreads();
    if (d < NCLS) {
        float acc = bcls[d];
        for (int j = 0; j < DD; ++j) acc += pooled[j] * Wcls[j * NCLS + d];
        out[b * NCLS + d] = acc;
    }
}

extern "C" void kernel_launch(void* const* d_in, const int* in_sizes, int n_in,
                              void* d_out, int out_size, void* d_ws, size_t ws_size,
                              hipStream_t stream) {
    const int* tokens      = (const int*)d_in[0];
    const float* emb       = (const float*)d_in[1];
    const float* theta_att = (const float*)d_in[2];
    const float* Wc        = (const float*)d_in[3];
    const float* bc        = (const float*)d_in[4];
    const float* ln1_g     = (const float*)d_in[5];
    const float* ln1_b     = (const float*)d_in[6];
    const float* theta_ffn = (const float*)d_in[7];
    const float* W1        = (const float*)d_in[8];
    const float* b1        = (const float*)d_in[9];
    const float* W2        = (const float*)d_in[10];
    const float* b2        = (const float*)d_in[11];
    const float* ln2_g     = (const float*)d_in[12];
    const float* ln2_b     = (const float*)d_in[13];
    const float* Wcls      = (const float*)d_in[14];
    const float* bcls      = (const float*)d_in[15];
    float* out = (float*)d_out;

    char* wsb = (char*)d_ws;
    float* x   = (float*)(wsb);                         // 16 MB
    float* t0  = (float*)(wsb + (size_t)16 * 1048576);  // 16 MB
    short* p   = (short*)(wsb + (size_t)32 * 1048576);  // 8 MB
    short* pt  = (short*)(wsb + (size_t)40 * 1048576);  // 8 MB
    short* a   = (short*)(wsb + (size_t)48 * 1048576);  // 8 MB
    short* hh  = (short*)(wsb + (size_t)56 * 1048576);  // 32 MB
    short* Wct = (short*)(wsb + (size_t)88 * 1048576);  // 0.5 MB
    short* W1t = (short*)(wsb + (size_t)89 * 1048576);  // 2 MB
    short* W2t = (short*)(wsb + (size_t)91 * 1048576);  // 2 MB

    k_embed_pe<<<ROWS, 128, 0, stream>>>(tokens, emb, x);

    for (int l = 0; l < NLAYERS; ++l) {
        // weight prep (transpose + bf16)
        k_wtrans<<<dim3(DD / 32, DD / 32), 256, 0, stream>>>(Wc + (size_t)l * DD * DD, Wct, DD, DD);
        k_wtrans<<<dim3(FF / 32, DD / 32), 256, 0, stream>>>(W1 + (size_t)l * DD * FF, W1t, DD, FF);
        k_wtrans<<<dim3(DD / 32, FF / 32), 256, 0, stream>>>(W2 + (size_t)l * FF * DD, W2t, FF, DD);

        // --- MHA ---
        k_cosp<1><<<dim3(DD / 64, SS / 64, BB), 256, 0, stream>>>(x, theta_att + l * DD, p, pt);
        k_attn<<<dim3(SS / 64, HH, BB), 256, 0, stream>>>(p, pt, a);
        k_mm<0, 0><<<dim3(DD / 128, ROWS / 128), 256, 0, stream>>>(a, Wct, bc + l * DD, t0, DD, DD);
        k_add_ln<<<ROWS, 128, 0, stream>>>(x, t0, ln1_g + l * DD, ln1_b + l * DD);

        // --- FFN ---
        k_cosp<0><<<dim3(DD / 64, SS / 64, BB), 256, 0, stream>>>(x, theta_ffn + l * DD, p, p);
        k_mm<1, 1><<<dim3(FF / 128, ROWS / 128), 256, 0, stream>>>(p, W1t, b1 + l * FF, hh, FF, DD);
        k_mm<0, 0><<<dim3(DD / 128, ROWS / 128), 256, 0, stream>>>(hh, W2t, b2 + l * DD, t0, DD, FF);
        k_add_ln<<<ROWS, 128, 0, stream>>>(x, t0, ln2_g + l * DD, ln2_b + l * DD);
    }

    k_head<<<BB, 512, 0, stream>>>(x, Wcls, bcls, out);
}

// Round 3
// 478.895 us; speedup vs baseline: 5.7200x; 1.1202x over previous
//
#include <hip/hip_runtime.h>
#include <math.h>

#define BB 8
#define SS 1024
#define DD 512
#define HH 8
#define DK 64
#define FF 2048
#define NCLS 10
#define ROWS (BB*SS)   // 8192
#define NLAYERS 2

typedef short bf16x8 __attribute__((ext_vector_type(8)));
typedef float f32x4 __attribute__((ext_vector_type(4)));

__device__ inline short f2bf(float f) {
    unsigned u = __float_as_uint(f);
    u += 0x7FFF + ((u >> 16) & 1);          // round-to-nearest-even
    return (short)(u >> 16);
}

__device__ inline void gload_lds16(const void* g, void* l) {
    __builtin_amdgcn_global_load_lds((const __attribute__((address_space(1))) void*)g,
                                     (__attribute__((address_space(3))) void*)l, 16, 0, 0);
}

// ---------------- embedding + sinusoidal positional encoding ----------------
__global__ __launch_bounds__(128) void k_embed_pe(const int* __restrict__ tokens,
                                                  const float* __restrict__ emb,
                                                  float* __restrict__ x) {
    int row = blockIdx.x;            // b*S + s
    int s = row & (SS - 1);
    int tok = tokens[row];
    const float4* e = reinterpret_cast<const float4*>(emb + (size_t)tok * DD);
    float4 v = e[threadIdx.x];
    float pe[4];
#pragma unroll
    for (int j = 0; j < 4; ++j) {
        int d = threadIdx.x * 4 + j;
        int jj = d >> 1;
        float inv = expf(-((float)(2 * jj) / (float)DD) * 9.210340371976184f);
        float ang = (float)s * inv;
        pe[j] = (d & 1) ? cosf(ang) : sinf(ang);
    }
    v.x += pe[0]; v.y += pe[1]; v.z += pe[2]; v.w += pe[3];
    reinterpret_cast<float4*>(x + (size_t)row * DD)[threadIdx.x] = v;
}

// ---------------- fused cos-projection -> bf16 p, optionally transposed p_t ----
template <int WT>
__global__ __launch_bounds__(256) void k_cosp(const float* __restrict__ x,
                                              const float* __restrict__ theta,
                                              short* __restrict__ p,
                                              short* __restrict__ pt) {
    int d0 = blockIdx.x * 64, s0 = blockIdx.y * 64, b = blockIdx.z;
    int t = threadIdx.x;
    int tc = t & 15, tr = t >> 4;
    __shared__ short lt[64][68];
    float4 th = *reinterpret_cast<const float4*>(theta + d0 + tc * 4);
#pragma unroll
    for (int i = 0; i < 4; ++i) {
        int s = tr + 16 * i;
        float4 xv = *reinterpret_cast<const float4*>(
            x + ((size_t)b * SS + s0 + s) * DD + d0 + tc * 4);
        short4 o;
        o.x = f2bf(cosf(xv.x + th.x));
        o.y = f2bf(cosf(xv.y + th.y));
        o.z = f2bf(cosf(xv.z + th.z));
        o.w = f2bf(cosf(xv.w + th.w));
        *reinterpret_cast<short4*>(p + ((size_t)b * SS + s0 + s) * DD + d0 + tc * 4) = o;
        if (WT) {
            lt[tc * 4 + 0][s] = o.x;
            lt[tc * 4 + 1][s] = o.y;
            lt[tc * 4 + 2][s] = o.z;
            lt[tc * 4 + 3][s] = o.w;
        }
    }
    if (WT) {
        __syncthreads();
#pragma unroll
        for (int i = 0; i < 4; ++i) {
            int d = tr + 16 * i;
            short4 v;
            v.x = lt[d][tc * 4 + 0];
            v.y = lt[d][tc * 4 + 1];
            v.z = lt[d][tc * 4 + 2];
            v.w = lt[d][tc * 4 + 3];
            *reinterpret_cast<short4*>(pt + ((size_t)b * DD + d0 + d) * SS + s0 + tc * 4) = v;
        }
    }
}

// ---------------- weight transpose+convert: f32 [K][N] -> bf16 [N][K] ----------
__global__ __launch_bounds__(256) void k_wtrans(const float* __restrict__ W,
                                                short* __restrict__ Wt,
                                                int K, int N) {
    __shared__ float tile[32][33];
    int n0 = blockIdx.x * 32, k0 = blockIdx.y * 32;
    int tx = threadIdx.x & 31, ty = threadIdx.x >> 5;   // 32 x 8
#pragma unroll
    for (int i = 0; i < 4; ++i)
        tile[ty + 8 * i][tx] = W[(size_t)(k0 + ty + 8 * i) * N + n0 + tx];
    __syncthreads();
#pragma unroll
    for (int i = 0; i < 4; ++i)
        Wt[(size_t)(n0 + ty + 8 * i) * K + k0 + tx] = f2bf(tile[tx][ty + 8 * i]);
}

// ---------------- MFMA attention (q=k=v=p), streaming softmax, no max needed ---
__global__ __launch_bounds__(256) void k_attn(const short* __restrict__ p,
                                              const short* __restrict__ pt,
                                              short* __restrict__ aout) {
    int qc = blockIdx.x, h = blockIdx.y, b = blockIdx.z;
    int t = threadIdx.x, w = t >> 6, l = t & 63;
    int lg = l >> 4, lr = l & 15;

    __shared__ __attribute__((aligned(16))) short Kt[128 * 64];   // [k][d] 16KB
    __shared__ __attribute__((aligned(16))) short Vt[64 * 128];   // [d][k] 16KB
    __shared__ __attribute__((aligned(16))) short Pl[4][16 * 136]; // per-wave P [q][k]

    const size_t prow = ((size_t)b * SS + qc * 64 + w * 16 + lr) * DD + h * DK;
    bf16x8 qf0 = *reinterpret_cast<const bf16x8*>(p + prow + lg * 8);
    bf16x8 qf1 = *reinterpret_cast<const bf16x8*>(p + prow + 32 + lg * 8);

    f32x4 acc[4];
#pragma unroll
    for (int dt = 0; dt < 4; ++dt) acc[dt] = (f32x4){0.f, 0.f, 0.f, 0.f};
    float denom = 0.f;

    const short* pK = p + (size_t)b * SS * DD + h * DK;        // + k*DD
    const short* pV = pt + ((size_t)b * DD + h * DK) * SS;     // + d*SS

    short* myP = &Pl[w][0];

    for (int k0 = 0; k0 < SS; k0 += 128) {
        __syncthreads();
#pragma unroll
        for (int i = 0; i < 4; ++i) {
            int c = i * 256 + t;
            int row = c >> 3, sl = c & 7, ssl = sl ^ (row & 7);
            gload_lds16(pK + (size_t)(k0 + row) * DD + ssl * 8,
                        Kt + (size_t)(i * 256 + w * 64) * 8);
        }
#pragma unroll
        for (int i = 0; i < 4; ++i) {
            int c = i * 256 + t;
            int row = c >> 4, sl = c & 15, ssl = sl ^ ((row & 7) * 2);
            gload_lds16(pV + (size_t)row * SS + k0 + ssl * 8,
                        Vt + (size_t)(i * 256 + w * 64) * 8);
        }
        asm volatile("s_waitcnt vmcnt(0)" ::: "memory");
        __syncthreads();

        f32x4 sc[8];
#pragma unroll
        for (int kt = 0; kt < 8; ++kt) {
            int row = kt * 16 + lr;
            bf16x8 ka0 = *reinterpret_cast<const bf16x8*>(Kt + row * 64 + ((lg ^ (row & 7)) * 8));
            bf16x8 ka1 = *reinterpret_cast<const bf16x8*>(Kt + row * 64 + (((lg + 4) ^ (row & 7)) * 8));
            f32x4 z = (f32x4){0.f, 0.f, 0.f, 0.f};
            z = __builtin_amdgcn_mfma_f32_16x16x32_bf16(ka0, qf0, z, 0, 0, 0);
            z = __builtin_amdgcn_mfma_f32_16x16x32_bf16(ka1, qf1, z, 0, 0, 0);
            sc[kt] = z;
        }
#pragma unroll
        for (int kt = 0; kt < 8; ++kt) {
            float e0 = __expf(sc[kt].x * 0.125f);
            float e1 = __expf(sc[kt].y * 0.125f);
            float e2 = __expf(sc[kt].z * 0.125f);
            float e3 = __expf(sc[kt].w * 0.125f);
            denom += (e0 + e1) + (e2 + e3);
            short4 pk;
            pk.x = f2bf(e0); pk.y = f2bf(e1); pk.z = f2bf(e2); pk.w = f2bf(e3);
            *reinterpret_cast<short4*>(myP + lr * 136 + kt * 16 + lg * 4) = pk;
        }
        asm volatile("s_waitcnt lgkmcnt(0)" ::: "memory");
#pragma unroll
        for (int kt2 = 0; kt2 < 4; ++kt2) {
            bf16x8 pb = *reinterpret_cast<const bf16x8*>(myP + lr * 136 + kt2 * 32 + lg * 8);
#pragma unroll
            for (int dt = 0; dt < 4; ++dt) {
                int row = dt * 16 + lr;
                bf16x8 va = *reinterpret_cast<const bf16x8*>(
                    Vt + row * 128 + (((kt2 * 4 + lg) ^ ((row & 7) * 2)) * 8));
                acc[dt] = __builtin_amdgcn_mfma_f32_16x16x32_bf16(va, pb, acc[dt], 0, 0, 0);
            }
        }
    }

    denom += __shfl_xor(denom, 16);
    denom += __shfl_xor(denom, 32);
    float inv = 1.0f / denom;

    size_t orow = ((size_t)b * SS + qc * 64 + w * 16 + lr) * DD + h * DK;
#pragma unroll
    for (int dt = 0; dt < 4; ++dt) {
        short4 o;
        o.x = f2bf(acc[dt].x * inv);
        o.y = f2bf(acc[dt].y * inv);
        o.z = f2bf(acc[dt].z * inv);
        o.w = f2bf(acc[dt].w * inv);
        *reinterpret_cast<short4*>(aout + orow + dt * 16 + lg * 4) = o;
    }
}

// ---------------- bf16 MFMA GEMM: C[M,N] = A[M,K] * W[K,N] + bias ---------------
template <int RELU, int OUTBF>
__global__ __launch_bounds__(256) void k_mm(const short* __restrict__ A,
                                            const short* __restrict__ Bt,
                                            const float* __restrict__ bias,
                                            void* __restrict__ C,
                                            int N, int K) {
    __shared__ __attribute__((aligned(16))) short Al[128 * 32];
    __shared__ __attribute__((aligned(16))) short Bl[128 * 32];
    int t = threadIdx.x, w = t >> 6, l = t & 63;
    int lg = l >> 4, lr = l & 15;
    int wm = w >> 1, wn = w & 1;
    int row0 = blockIdx.y * 128, col0 = blockIdx.x * 128;

    f32x4 acc[4][4];
#pragma unroll
    for (int m = 0; m < 4; ++m)
#pragma unroll
        for (int n = 0; n < 4; ++n) acc[m][n] = (f32x4){0.f, 0.f, 0.f, 0.f};

    for (int k0 = 0; k0 < K; k0 += 32) {
        __syncthreads();
#pragma unroll
        for (int i = 0; i < 2; ++i) {
            int c = i * 256 + t;
            int row = c >> 2, sl = c & 3, ssl = sl ^ ((row >> 1) & 3);
            gload_lds16(A + (size_t)(row0 + row) * K + k0 + ssl * 8,
                        Al + (size_t)(i * 256 + w * 64) * 8);
            gload_lds16(Bt + (size_t)(col0 + row) * K + k0 + ssl * 8,
                        Bl + (size_t)(i * 256 + w * 64) * 8);
        }
        asm volatile("s_waitcnt vmcnt(0)" ::: "memory");
        __syncthreads();

        bf16x8 af[4], bfr[4];
#pragma unroll
        for (int m = 0; m < 4; ++m) {
            int row = wm * 64 + m * 16 + lr;
            af[m] = *reinterpret_cast<const bf16x8*>(Al + row * 32 + ((lg ^ ((row >> 1) & 3)) * 8));
        }
#pragma unroll
        for (int n = 0; n < 4; ++n) {
            int row = wn * 64 + n * 16 + lr;
            bfr[n] = *reinterpret_cast<const bf16x8*>(Bl + row * 32 + ((lg ^ ((row >> 1) & 3)) * 8));
        }
#pragma unroll
        for (int m = 0; m < 4; ++m)
#pragma unroll
            for (int n = 0; n < 4; ++n)
                acc[m][n] = __builtin_amdgcn_mfma_f32_16x16x32_bf16(af[m], bfr[n], acc[m][n], 0, 0, 0);
    }

    float bv[4];
#pragma unroll
    for (int n = 0; n < 4; ++n) bv[n] = bias[col0 + wn * 64 + n * 16 + lr];

#pragma unroll
    for (int m = 0; m < 4; ++m) {
#pragma unroll
        for (int n = 0; n < 4; ++n) {
            int col = col0 + wn * 64 + n * 16 + lr;
#pragma unroll
            for (int j = 0; j < 4; ++j) {
                int row = row0 + wm * 64 + m * 16 + lg * 4 + j;
                float v = acc[m][n][j] + bv[n];
                if (RELU) v = fmaxf(v, 0.f);
                if (OUTBF) ((short*)C)[(size_t)row * N + col] = f2bf(v);
                else       ((float*)C)[(size_t)row * N + col] = v;
            }
        }
    }
}

// ------- x = LayerNorm(x + r)*g + b; optionally also p = bf16(cos(x + theta)) ----
template <int COSP>
__global__ __launch_bounds__(128) void k_add_ln(float* __restrict__ x,
                                                const float* __restrict__ rr,
                                                const float* __restrict__ g,
                                                const float* __restrict__ bb,
                                                const float* __restrict__ theta,
                                                short* __restrict__ p) {
    int row = blockIdx.x;
    int t = threadIdx.x;
    float4 v = *reinterpret_cast<const float4*>(x + (size_t)row * DD + t * 4);
    float4 av = *reinterpret_cast<const float4*>(rr + (size_t)row * DD + t * 4);
    v.x += av.x; v.y += av.y; v.z += av.z; v.w += av.w;
    float s = v.x + v.y + v.z + v.w;
    float s2 = v.x * v.x + v.y * v.y + v.z * v.z + v.w * v.w;
#pragma unroll
    for (int off = 32; off > 0; off >>= 1) {
        s += __shfl_down(s, off);
        s2 += __shfl_down(s2, off);
    }
    __shared__ float ls[2], ls2[2];
    if ((t & 63) == 0) { ls[t >> 6] = s; ls2[t >> 6] = s2; }
    __syncthreads();
    float S1 = ls[0] + ls[1];
    float S2 = ls2[0] + ls2[1];
    float mu = S1 * (1.0f / DD);
    float var = S2 * (1.0f / DD) - mu * mu;
    float rstd = rsqrtf(var + 1e-5f);
    float4 gv = *reinterpret_cast<const float4*>(g + t * 4);
    float4 bv = *reinterpret_cast<const float4*>(bb + t * 4);
    float4 o;
    o.x = gv.x * (v.x - mu) * rstd + bv.x;
    o.y = gv.y * (v.y - mu) * rstd + bv.y;
    o.z = gv.z * (v.z - mu) * rstd + bv.z;
    o.w = gv.w * (v.w - mu) * rstd + bv.w;
    *reinterpret_cast<float4*>(x + (size_t)row * DD + t * 4) = o;
    if (COSP) {
        float4 th = *reinterpret_cast<const float4*>(theta + t * 4);
        short4 pk;
        pk.x = f2bf(cosf(o.x + th.x));
        pk.y = f2bf(cosf(o.y + th.y));
        pk.z = f2bf(cosf(o.z + th.z));
        pk.w = f2bf(cosf(o.w + th.w));
        *reinterpret_cast<short4*>(p + (size_t)row * DD + t * 4) = pk;
    }
}

// ---------------- mean-pool stage 1: partial sums over 32-row chunks ------------
__global__ __launch_bounds__(128) void k_pool(const float* __restrict__ x,
                                              float* __restrict__ part) {
    int b = blockIdx.x, c = blockIdx.y;     // 8 x 32
    int t = threadIdx.x;                    // 128 threads x float4
    float4 s = {0.f, 0.f, 0.f, 0.f};
    for (int i = 0; i < 32; ++i) {
        float4 v = reinterpret_cast<const float4*>(
            x + ((size_t)b * SS + c * 32 + i) * DD)[t];
        s.x += v.x; s.y += v.y; s.z += v.z; s.w += v.w;
    }
    reinterpret_cast<float4*>(part + ((size_t)b * 32 + c) * DD)[t] = s;
}

// ---------------- pool stage 2 + classifier ----------------
__global__ __launch_bounds__(512) void k_cls(const float* __restrict__ part,
                                             const float* __restrict__ Wcls,
                                             const float* __restrict__ bcls,
                                             float* __restrict__ out) {
    int b = blockIdx.x;
    int t = threadIdx.x;                    // d = t
    float s = 0.f;
    for (int i = 0; i < 32; ++i) s += part[((size_t)b * 32 + i) * DD + t];
    float pooled = s * (1.0f / SS);
    float acc[NCLS];
#pragma unroll
    for (int c = 0; c < NCLS; ++c) acc[c] = pooled * Wcls[t * NCLS + c];
#pragma unroll
    for (int off = 32; off > 0; off >>= 1)
#pragma unroll
        for (int c = 0; c < NCLS; ++c) acc[c] += __shfl_xor(acc[c], off);
    __shared__ float wp[8][NCLS];
    int w = t >> 6, l = t & 63;
    if (l == 0)
#pragma unroll
        for (int c = 0; c < NCLS; ++c) wp[w][c] = acc[c];
    __syncthreads();
    if (t < NCLS) {
        float o = bcls[t];
#pragma unroll
        for (int i = 0; i < 8; ++i) o += wp[i][t];
        out[b * NCLS + t] = o;
    }
}

extern "C" void kernel_launch(void* const* d_in, const int* in_sizes, int n_in,
                              void* d_out, int out_size, void* d_ws, size_t ws_size,
                              hipStream_t stream) {
    const int* tokens      = (const int*)d_in[0];
    const float* emb       = (const float*)d_in[1];
    const float* theta_att = (const float*)d_in[2];
    const float* Wc        = (const float*)d_in[3];
    const float* bc        = (const float*)d_in[4];
    const float* ln1_g     = (const float*)d_in[5];
    const float* ln1_b     = (const float*)d_in[6];
    const float* theta_ffn = (const float*)d_in[7];
    const float* W1        = (const float*)d_in[8];
    const float* b1        = (const float*)d_in[9];
    const float* W2        = (const float*)d_in[10];
    const float* b2        = (const float*)d_in[11];
    const float* ln2_g     = (const float*)d_in[12];
    const float* ln2_b     = (const float*)d_in[13];
    const float* Wcls      = (const float*)d_in[14];
    const float* bcls      = (const float*)d_in[15];
    float* out = (float*)d_out;

    char* wsb = (char*)d_ws;
    float* x    = (float*)(wsb);                         // 16 MB
    float* t0   = (float*)(wsb + (size_t)16 * 1048576);  // 16 MB
    short* p    = (short*)(wsb + (size_t)32 * 1048576);  // 8 MB
    short* pt   = (short*)(wsb + (size_t)40 * 1048576);  // 8 MB
    short* a    = (short*)(wsb + (size_t)48 * 1048576);  // 8 MB
    short* hh   = (short*)(wsb + (size_t)56 * 1048576);  // 32 MB
    short* Wct  = (short*)(wsb + (size_t)88 * 1048576);  // 0.5 MB
    short* W1t  = (short*)(wsb + (size_t)89 * 1048576);  // 2 MB
    short* W2t  = (short*)(wsb + (size_t)91 * 1048576);  // 2 MB
    float* part = (float*)(wsb + (size_t)94 * 1048576);  // 0.5 MB

    k_embed_pe<<<ROWS, 128, 0, stream>>>(tokens, emb, x);

    for (int l = 0; l < NLAYERS; ++l) {
        k_wtrans<<<dim3(DD / 32, DD / 32), 256, 0, stream>>>(Wc + (size_t)l * DD * DD, Wct, DD, DD);
        k_wtrans<<<dim3(FF / 32, DD / 32), 256, 0, stream>>>(W1 + (size_t)l * DD * FF, W1t, DD, FF);
        k_wtrans<<<dim3(DD / 32, FF / 32), 256, 0, stream>>>(W2 + (size_t)l * FF * DD, W2t, FF, DD);

        // --- MHA ---
        k_cosp<1><<<dim3(DD / 64, SS / 64, BB), 256, 0, stream>>>(x, theta_att + l * DD, p, pt);
        k_attn<<<dim3(SS / 64, HH, BB), 256, 0, stream>>>(p, pt, a);
        k_mm<0, 0><<<dim3(DD / 128, ROWS / 128), 256, 0, stream>>>(a, Wct, bc + l * DD, t0, DD, DD);
        // ln1 fused with FFN cos-projection
        k_add_ln<1><<<ROWS, 128, 0, stream>>>(x, t0, ln1_g + l * DD, ln1_b + l * DD,
                                              theta_ffn + l * DD, p);
        // --- FFN ---
        k_mm<1, 1><<<dim3(FF / 128, ROWS / 128), 256, 0, stream>>>(p, W1t, b1 + l * FF, hh, FF, DD);
        k_mm<0, 0><<<dim3(DD / 128, ROWS / 128), 256, 0, stream>>>(hh, W2t, b2 + l * DD, t0, DD, FF);
        k_add_ln<0><<<ROWS, 128, 0, stream>>>(x, t0, ln2_g + l * DD, ln2_b + l * DD,
                                              (const float*)nullptr, (short*)nullptr);
    }

    k_pool<<<dim3(BB, 32), 128, 0, stream>>>(x, part);
    k_cls<<<BB, 512, 0, stream>>>(part, Wcls, bcls, out);
}

// Round 4
// 463.526 us; speedup vs baseline: 5.9096x; 1.0332x over previous
//
#include <hip/hip_runtime.h>
#include <math.h>

#define BB 8
#define SS 1024
#define DD 512
#define HH 8
#define DK 64
#define FF 2048
#define NCLS 10
#define ROWS (BB*SS)   // 8192
#define NLAYERS 2

typedef short bf16x8 __attribute__((ext_vector_type(8)));
typedef float f32x4 __attribute__((ext_vector_type(4)));

__device__ inline short f2bf(float f) {
    unsigned u = __float_as_uint(f);
    u += 0x7FFF + ((u >> 16) & 1);          // round-to-nearest-even
    return (short)(u >> 16);
}

__device__ inline void gload_lds16(const void* g, void* l) {
    __builtin_amdgcn_global_load_lds((const __attribute__((address_space(1))) void*)g,
                                     (__attribute__((address_space(3))) void*)l, 16, 0, 0);
}

// ---------------- embedding + sinusoidal positional encoding ----------------
__global__ __launch_bounds__(128) void k_embed_pe(const int* __restrict__ tokens,
                                                  const float* __restrict__ emb,
                                                  float* __restrict__ x) {
    int row = blockIdx.x;            // b*S + s
    int s = row & (SS - 1);
    int tok = tokens[row];
    const float4* e = reinterpret_cast<const float4*>(emb + (size_t)tok * DD);
    float4 v = e[threadIdx.x];
    float pe[4];
#pragma unroll
    for (int j = 0; j < 4; ++j) {
        int d = threadIdx.x * 4 + j;
        int jj = d >> 1;
        float inv = expf(-((float)(2 * jj) / (float)DD) * 9.210340371976184f);
        float ang = (float)s * inv;
        pe[j] = (d & 1) ? cosf(ang) : sinf(ang);
    }
    v.x += pe[0]; v.y += pe[1]; v.z += pe[2]; v.w += pe[3];
    reinterpret_cast<float4*>(x + (size_t)row * DD)[threadIdx.x] = v;
}

// ---------------- fused cos-projection -> bf16 p, optionally transposed p_t ----
template <int WT>
__global__ __launch_bounds__(256) void k_cosp(const float* __restrict__ x,
                                              const float* __restrict__ theta,
                                              short* __restrict__ p,
                                              short* __restrict__ pt) {
    int d0 = blockIdx.x * 64, s0 = blockIdx.y * 64, b = blockIdx.z;
    int t = threadIdx.x;
    int tc = t & 15, tr = t >> 4;
    __shared__ short lt[64][68];
    float4 th = *reinterpret_cast<const float4*>(theta + d0 + tc * 4);
#pragma unroll
    for (int i = 0; i < 4; ++i) {
        int s = tr + 16 * i;
        float4 xv = *reinterpret_cast<const float4*>(
            x + ((size_t)b * SS + s0 + s) * DD + d0 + tc * 4);
        short4 o;
        o.x = f2bf(cosf(xv.x + th.x));
        o.y = f2bf(cosf(xv.y + th.y));
        o.z = f2bf(cosf(xv.z + th.z));
        o.w = f2bf(cosf(xv.w + th.w));
        *reinterpret_cast<short4*>(p + ((size_t)b * SS + s0 + s) * DD + d0 + tc * 4) = o;
        if (WT) {
            lt[tc * 4 + 0][s] = o.x;
            lt[tc * 4 + 1][s] = o.y;
            lt[tc * 4 + 2][s] = o.z;
            lt[tc * 4 + 3][s] = o.w;
        }
    }
    if (WT) {
        __syncthreads();
#pragma unroll
        for (int i = 0; i < 4; ++i) {
            int d = tr + 16 * i;
            short4 v;
            v.x = lt[d][tc * 4 + 0];
            v.y = lt[d][tc * 4 + 1];
            v.z = lt[d][tc * 4 + 2];
            v.w = lt[d][tc * 4 + 3];
            *reinterpret_cast<short4*>(pt + ((size_t)b * DD + d0 + d) * SS + s0 + tc * 4) = v;
        }
    }
}

// ---------------- weight transpose+convert: f32 [K][N] -> bf16 [N][K] ----------
__global__ __launch_bounds__(256) void k_wtrans(const float* __restrict__ W,
                                                short* __restrict__ Wt,
                                                int K, int N) {
    __shared__ float tile[32][33];
    int n0 = blockIdx.x * 32, k0 = blockIdx.y * 32;
    int tx = threadIdx.x & 31, ty = threadIdx.x >> 5;   // 32 x 8
#pragma unroll
    for (int i = 0; i < 4; ++i)
        tile[ty + 8 * i][tx] = W[(size_t)(k0 + ty + 8 * i) * N + n0 + tx];
    __syncthreads();
#pragma unroll
    for (int i = 0; i < 4; ++i)
        Wt[(size_t)(n0 + ty + 8 * i) * K + k0 + tx] = f2bf(tile[tx][ty + 8 * i]);
}

// ---------------- MFMA attention (q=k=v=p), streaming softmax, no max needed ---
__global__ __launch_bounds__(256) void k_attn(const short* __restrict__ p,
                                              const short* __restrict__ pt,
                                              short* __restrict__ aout) {
    int qc = blockIdx.x, h = blockIdx.y, b = blockIdx.z;
    int t = threadIdx.x, w = t >> 6, l = t & 63;
    int lg = l >> 4, lr = l & 15;

    __shared__ __attribute__((aligned(16))) short Kt[128 * 64];   // [k][d] 16KB
    __shared__ __attribute__((aligned(16))) short Vt[64 * 128];   // [d][k] 16KB
    __shared__ __attribute__((aligned(16))) short Pl[4][16 * 136]; // per-wave P [q][k]

    const size_t prow = ((size_t)b * SS + qc * 64 + w * 16 + lr) * DD + h * DK;
    bf16x8 qf0 = *reinterpret_cast<const bf16x8*>(p + prow + lg * 8);
    bf16x8 qf1 = *reinterpret_cast<const bf16x8*>(p + prow + 32 + lg * 8);

    f32x4 acc[4];
#pragma unroll
    for (int dt = 0; dt < 4; ++dt) acc[dt] = (f32x4){0.f, 0.f, 0.f, 0.f};
    float denom = 0.f;

    const short* pK = p + (size_t)b * SS * DD + h * DK;        // + k*DD
    const short* pV = pt + ((size_t)b * DD + h * DK) * SS;     // + d*SS

    short* myP = &Pl[w][0];

    for (int k0 = 0; k0 < SS; k0 += 128) {
        __syncthreads();
#pragma unroll
        for (int i = 0; i < 4; ++i) {
            int c = i * 256 + t;
            int row = c >> 3, sl = c & 7, ssl = sl ^ (row & 7);
            gload_lds16(pK + (size_t)(k0 + row) * DD + ssl * 8,
                        Kt + (size_t)(i * 256 + w * 64) * 8);
        }
#pragma unroll
        for (int i = 0; i < 4; ++i) {
            int c = i * 256 + t;
            int row = c >> 4, sl = c & 15, ssl = sl ^ ((row & 7) * 2);
            gload_lds16(pV + (size_t)row * SS + k0 + ssl * 8,
                        Vt + (size_t)(i * 256 + w * 64) * 8);
        }
        asm volatile("s_waitcnt vmcnt(0)" ::: "memory");
        __syncthreads();

        f32x4 sc[8];
#pragma unroll
        for (int kt = 0; kt < 8; ++kt) {
            int row = kt * 16 + lr;
            bf16x8 ka0 = *reinterpret_cast<const bf16x8*>(Kt + row * 64 + ((lg ^ (row & 7)) * 8));
            bf16x8 ka1 = *reinterpret_cast<const bf16x8*>(Kt + row * 64 + (((lg + 4) ^ (row & 7)) * 8));
            f32x4 z = (f32x4){0.f, 0.f, 0.f, 0.f};
            z = __builtin_amdgcn_mfma_f32_16x16x32_bf16(ka0, qf0, z, 0, 0, 0);
            z = __builtin_amdgcn_mfma_f32_16x16x32_bf16(ka1, qf1, z, 0, 0, 0);
            sc[kt] = z;
        }
#pragma unroll
        for (int kt = 0; kt < 8; ++kt) {
            float e0 = __expf(sc[kt].x * 0.125f);
            float e1 = __expf(sc[kt].y * 0.125f);
            float e2 = __expf(sc[kt].z * 0.125f);
            float e3 = __expf(sc[kt].w * 0.125f);
            denom += (e0 + e1) + (e2 + e3);
            short4 pk;
            pk.x = f2bf(e0); pk.y = f2bf(e1); pk.z = f2bf(e2); pk.w = f2bf(e3);
            *reinterpret_cast<short4*>(myP + lr * 136 + kt * 16 + lg * 4) = pk;
        }
        asm volatile("s_waitcnt lgkmcnt(0)" ::: "memory");
#pragma unroll
        for (int kt2 = 0; kt2 < 4; ++kt2) {
            bf16x8 pb = *reinterpret_cast<const bf16x8*>(myP + lr * 136 + kt2 * 32 + lg * 8);
#pragma unroll
            for (int dt = 0; dt < 4; ++dt) {
                int row = dt * 16 + lr;
                bf16x8 va = *reinterpret_cast<const bf16x8*>(
                    Vt + row * 128 + (((kt2 * 4 + lg) ^ ((row & 7) * 2)) * 8));
                acc[dt] = __builtin_amdgcn_mfma_f32_16x16x32_bf16(va, pb, acc[dt], 0, 0, 0);
            }
        }
    }

    denom += __shfl_xor(denom, 16);
    denom += __shfl_xor(denom, 32);
    float inv = 1.0f / denom;

    size_t orow = ((size_t)b * SS + qc * 64 + w * 16 + lr) * DD + h * DK;
#pragma unroll
    for (int dt = 0; dt < 4; ++dt) {
        short4 o;
        o.x = f2bf(acc[dt].x * inv);
        o.y = f2bf(acc[dt].y * inv);
        o.z = f2bf(acc[dt].z * inv);
        o.w = f2bf(acc[dt].w * inv);
        *reinterpret_cast<short4*>(aout + orow + dt * 16 + lg * 4) = o;
    }
}

// ---------------- bf16 MFMA GEMM: C[M,N] = A[M,K] * W[K,N] + bias ---------------
// 128x128 tile, BK=32, 4 waves 2x2, DOUBLE-BUFFERED 2-phase K-loop, XCD swizzle.
// grid: 1-D nwg = (N/128)*(M/128), gx = N/128.
template <int RELU, int OUTBF>
__global__ __launch_bounds__(256) void k_mm(const short* __restrict__ A,
                                            const short* __restrict__ Bt,
                                            const float* __restrict__ bias,
                                            void* __restrict__ C,
                                            int N, int K, int gx) {
    __shared__ __attribute__((aligned(16))) short Al[2][128 * 32];
    __shared__ __attribute__((aligned(16))) short Bl[2][128 * 32];
    int t = threadIdx.x, w = t >> 6, l = t & 63;
    int lg = l >> 4, lr = l & 15;
    int wm = w >> 1, wn = w & 1;

    // bijective XCD swizzle: group consecutive logical tiles on one XCD
    int nwg = gridDim.x;
    int bid = blockIdx.x;
    int swz = (bid & 7) * (nwg >> 3) + (bid >> 3);
    int bx = swz % gx, by = swz / gx;
    int row0 = by * 128, col0 = bx * 128;

    f32x4 acc[4][4];
#pragma unroll
    for (int m = 0; m < 4; ++m)
#pragma unroll
        for (int n = 0; n < 4; ++n) acc[m][n] = (f32x4){0.f, 0.f, 0.f, 0.f};

#define STAGE_MM(buf, kk0)                                                      \
    {                                                                           \
        _Pragma("unroll")                                                       \
        for (int i = 0; i < 2; ++i) {                                           \
            int c = i * 256 + t;                                                \
            int row = c >> 2, sl = c & 3, ssl = sl ^ ((row >> 1) & 3);          \
            gload_lds16(A + (size_t)(row0 + row) * K + (kk0) + ssl * 8,         \
                        &Al[buf][0] + (size_t)(i * 256 + w * 64) * 8);          \
            gload_lds16(Bt + (size_t)(col0 + row) * K + (kk0) + ssl * 8,        \
                        &Bl[buf][0] + (size_t)(i * 256 + w * 64) * 8);          \
        }                                                                       \
    }

    // prologue: stage tile 0
    STAGE_MM(0, 0);
    asm volatile("s_waitcnt vmcnt(0)" ::: "memory");
    __syncthreads();

    const int nk = K >> 5;
    int cur = 0;
    for (int kt = 0; kt < nk; ++kt) {
        if (kt + 1 < nk) STAGE_MM(cur ^ 1, (kt + 1) * 32);

        const short* a_ = &Al[cur][0];
        const short* b_ = &Bl[cur][0];
        bf16x8 af[4], bfr[4];
#pragma unroll
        for (int m = 0; m < 4; ++m) {
            int row = wm * 64 + m * 16 + lr;
            af[m] = *reinterpret_cast<const bf16x8*>(a_ + row * 32 + ((lg ^ ((row >> 1) & 3)) * 8));
        }
#pragma unroll
        for (int n = 0; n < 4; ++n) {
            int row = wn * 64 + n * 16 + lr;
            bfr[n] = *reinterpret_cast<const bf16x8*>(b_ + row * 32 + ((lg ^ ((row >> 1) & 3)) * 8));
        }
#pragma unroll
        for (int m = 0; m < 4; ++m)
#pragma unroll
            for (int n = 0; n < 4; ++n)
                acc[m][n] = __builtin_amdgcn_mfma_f32_16x16x32_bf16(af[m], bfr[n], acc[m][n], 0, 0, 0);

        if (kt + 1 < nk) {
            asm volatile("s_waitcnt vmcnt(0)" ::: "memory");
            __syncthreads();
            cur ^= 1;
        }
    }
#undef STAGE_MM

    float bv[4];
#pragma unroll
    for (int n = 0; n < 4; ++n) bv[n] = bias[col0 + wn * 64 + n * 16 + lr];

#pragma unroll
    for (int m = 0; m < 4; ++m) {
#pragma unroll
        for (int n = 0; n < 4; ++n) {
            int col = col0 + wn * 64 + n * 16 + lr;
#pragma unroll
            for (int j = 0; j < 4; ++j) {
                int row = row0 + wm * 64 + m * 16 + lg * 4 + j;
                float v = acc[m][n][j] + bv[n];
                if (RELU) v = fmaxf(v, 0.f);
                if (OUTBF) ((short*)C)[(size_t)row * N + col] = f2bf(v);
                else       ((float*)C)[(size_t)row * N + col] = v;
            }
        }
    }
}

// ------- x = LayerNorm(x + r)*g + b; optionally also p = bf16(cos(x + theta)) ----
template <int COSP>
__global__ __launch_bounds__(128) void k_add_ln(float* __restrict__ x,
                                                const float* __restrict__ rr,
                                                const float* __restrict__ g,
                                                const float* __restrict__ bb,
                                                const float* __restrict__ theta,
                                                short* __restrict__ p) {
    int row = blockIdx.x;
    int t = threadIdx.x;
    float4 v = *reinterpret_cast<const float4*>(x + (size_t)row * DD + t * 4);
    float4 av = *reinterpret_cast<const float4*>(rr + (size_t)row * DD + t * 4);
    v.x += av.x; v.y += av.y; v.z += av.z; v.w += av.w;
    float s = v.x + v.y + v.z + v.w;
    float s2 = v.x * v.x + v.y * v.y + v.z * v.z + v.w * v.w;
#pragma unroll
    for (int off = 32; off > 0; off >>= 1) {
        s += __shfl_down(s, off);
        s2 += __shfl_down(s2, off);
    }
    __shared__ float ls[2], ls2[2];
    if ((t & 63) == 0) { ls[t >> 6] = s; ls2[t >> 6] = s2; }
    __syncthreads();
    float S1 = ls[0] + ls[1];
    float S2 = ls2[0] + ls2[1];
    float mu = S1 * (1.0f / DD);
    float var = S2 * (1.0f / DD) - mu * mu;
    float rstd = rsqrtf(var + 1e-5f);
    float4 gv = *reinterpret_cast<const float4*>(g + t * 4);
    float4 bv = *reinterpret_cast<const float4*>(bb + t * 4);
    float4 o;
    o.x = gv.x * (v.x - mu) * rstd + bv.x;
    o.y = gv.y * (v.y - mu) * rstd + bv.y;
    o.z = gv.z * (v.z - mu) * rstd + bv.z;
    o.w = gv.w * (v.w - mu) * rstd + bv.w;
    *reinterpret_cast<float4*>(x + (size_t)row * DD + t * 4) = o;
    if (COSP) {
        float4 th = *reinterpret_cast<const float4*>(theta + t * 4);
        short4 pk;
        pk.x = f2bf(cosf(o.x + th.x));
        pk.y = f2bf(cosf(o.y + th.y));
        pk.z = f2bf(cosf(o.z + th.z));
        pk.w = f2bf(cosf(o.w + th.w));
        *reinterpret_cast<short4*>(p + (size_t)row * DD + t * 4) = pk;
    }
}

// ---------------- mean-pool stage 1: partial sums over 32-row chunks ------------
__global__ __launch_bounds__(128) void k_pool(const float* __restrict__ x,
                                              float* __restrict__ part) {
    int b = blockIdx.x, c = blockIdx.y;     // 8 x 32
    int t = threadIdx.x;                    // 128 threads x float4
    float4 s = {0.f, 0.f, 0.f, 0.f};
    for (int i = 0; i < 32; ++i) {
        float4 v = reinterpret_cast<const float4*>(
            x + ((size_t)b * SS + c * 32 + i) * DD)[t];
        s.x += v.x; s.y += v.y; s.z += v.z; s.w += v.w;
    }
    reinterpret_cast<float4*>(part + ((size_t)b * 32 + c) * DD)[t] = s;
}

// ---------------- pool stage 2 + classifier ----------------
__global__ __launch_bounds__(512) void k_cls(const float* __restrict__ part,
                                             const float* __restrict__ Wcls,
                                             const float* __restrict__ bcls,
                                             float* __restrict__ out) {
    int b = blockIdx.x;
    int t = threadIdx.x;                    // d = t
    float s = 0.f;
    for (int i = 0; i < 32; ++i) s += part[((size_t)b * 32 + i) * DD + t];
    float pooled = s * (1.0f / SS);
    float acc[NCLS];
#pragma unroll
    for (int c = 0; c < NCLS; ++c) acc[c] = pooled * Wcls[t * NCLS + c];
#pragma unroll
    for (int off = 32; off > 0; off >>= 1)
#pragma unroll
        for (int c = 0; c < NCLS; ++c) acc[c] += __shfl_xor(acc[c], off);
    __shared__ float wp[8][NCLS];
    int w = t >> 6, l = t & 63;
    if (l == 0)
#pragma unroll
        for (int c = 0; c < NCLS; ++c) wp[w][c] = acc[c];
    __syncthreads();
    if (t < NCLS) {
        float o = bcls[t];
#pragma unroll
        for (int i = 0; i < 8; ++i) o += wp[i][t];
        out[b * NCLS + t] = o;
    }
}

extern "C" void kernel_launch(void* const* d_in, const int* in_sizes, int n_in,
                              void* d_out, int out_size, void* d_ws, size_t ws_size,
                              hipStream_t stream) {
    const int* tokens      = (const int*)d_in[0];
    const float* emb       = (const float*)d_in[1];
    const float* theta_att = (const float*)d_in[2];
    const float* Wc        = (const float*)d_in[3];
    const float* bc        = (const float*)d_in[4];
    const float* ln1_g     = (const float*)d_in[5];
    const float* ln1_b     = (const float*)d_in[6];
    const float* theta_ffn = (const float*)d_in[7];
    const float* W1        = (const float*)d_in[8];
    const float* b1        = (const float*)d_in[9];
    const float* W2        = (const float*)d_in[10];
    const float* b2        = (const float*)d_in[11];
    const float* ln2_g     = (const float*)d_in[12];
    const float* ln2_b     = (const float*)d_in[13];
    const float* Wcls      = (const float*)d_in[14];
    const float* bcls      = (const float*)d_in[15];
    float* out = (float*)d_out;

    char* wsb = (char*)d_ws;
    float* x    = (float*)(wsb);                         // 16 MB
    float* t0   = (float*)(wsb + (size_t)16 * 1048576);  // 16 MB
    short* p    = (short*)(wsb + (size_t)32 * 1048576);  // 8 MB
    short* pt   = (short*)(wsb + (size_t)40 * 1048576);  // 8 MB
    short* a    = (short*)(wsb + (size_t)48 * 1048576);  // 8 MB
    short* hh   = (short*)(wsb + (size_t)56 * 1048576);  // 32 MB
    short* Wct  = (short*)(wsb + (size_t)88 * 1048576);  // 0.5 MB
    short* W1t  = (short*)(wsb + (size_t)89 * 1048576);  // 2 MB
    short* W2t  = (short*)(wsb + (size_t)91 * 1048576);  // 2 MB
    float* part = (float*)(wsb + (size_t)94 * 1048576);  // 0.5 MB

    k_embed_pe<<<ROWS, 128, 0, stream>>>(tokens, emb, x);

    for (int l = 0; l < NLAYERS; ++l) {
        k_wtrans<<<dim3(DD / 32, DD / 32), 256, 0, stream>>>(Wc + (size_t)l * DD * DD, Wct, DD, DD);
        k_wtrans<<<dim3(FF / 32, DD / 32), 256, 0, stream>>>(W1 + (size_t)l * DD * FF, W1t, DD, FF);
        k_wtrans<<<dim3(DD / 32, FF / 32), 256, 0, stream>>>(W2 + (size_t)l * FF * DD, W2t, FF, DD);

        // --- MHA ---
        k_cosp<1><<<dim3(DD / 64, SS / 64, BB), 256, 0, stream>>>(x, theta_att + l * DD, p, pt);
        k_attn<<<dim3(SS / 64, HH, BB), 256, 0, stream>>>(p, pt, a);
        k_mm<0, 0><<<(DD / 128) * (ROWS / 128), 256, 0, stream>>>(
            a, Wct, bc + l * DD, t0, DD, DD, DD / 128);
        // ln1 fused with FFN cos-projection
        k_add_ln<1><<<ROWS, 128, 0, stream>>>(x, t0, ln1_g + l * DD, ln1_b + l * DD,
                                              theta_ffn + l * DD, p);
        // --- FFN ---
        k_mm<1, 1><<<(FF / 128) * (ROWS / 128), 256, 0, stream>>>(
            p, W1t, b1 + l * FF, hh, FF, DD, FF / 128);
        k_mm<0, 0><<<(DD / 128) * (ROWS / 128), 256, 0, stream>>>(
            hh, W2t, b2 + l * DD, t0, DD, FF, DD / 128);
        k_add_ln<0><<<ROWS, 128, 0, stream>>>(x, t0, ln2_g + l * DD, ln2_b + l * DD,
                                              (const float*)nullptr, (short*)nullptr);
    }

    k_pool<<<dim3(BB, 32), 128, 0, stream>>>(x, part);
    k_cls<<<BB, 512, 0, stream>>>(part, Wcls, bcls, out);
}

// Round 5
// 426.796 us; speedup vs baseline: 6.4182x; 1.0861x over previous
//
#include <hip/hip_runtime.h>
#include <math.h>

#define BB 8
#define SS 1024
#define DD 512
#define HH 8
#define DK 64
#define FF 2048
#define NCLS 10
#define ROWS (BB*SS)   // 8192
#define NLAYERS 2

typedef short bf16x8 __attribute__((ext_vector_type(8)));
typedef float f32x4 __attribute__((ext_vector_type(4)));

__device__ inline short f2bf(float f) {
    unsigned u = __float_as_uint(f);
    u += 0x7FFF + ((u >> 16) & 1);          // round-to-nearest-even
    return (short)(u >> 16);
}

__device__ inline void gload_lds16(const void* g, void* l) {
    __builtin_amdgcn_global_load_lds((const __attribute__((address_space(1))) void*)g,
                                     (__attribute__((address_space(3))) void*)l, 16, 0, 0);
}

// ---------------- embedding + sinusoidal positional encoding ----------------
__global__ __launch_bounds__(128) void k_embed_pe(const int* __restrict__ tokens,
                                                  const float* __restrict__ emb,
                                                  float* __restrict__ x) {
    int row = blockIdx.x;            // b*S + s
    int s = row & (SS - 1);
    int tok = tokens[row];
    const float4* e = reinterpret_cast<const float4*>(emb + (size_t)tok * DD);
    float4 v = e[threadIdx.x];
    float pe[4];
#pragma unroll
    for (int j = 0; j < 4; ++j) {
        int d = threadIdx.x * 4 + j;
        int jj = d >> 1;
        float inv = expf(-((float)(2 * jj) / (float)DD) * 9.210340371976184f);
        float ang = (float)s * inv;
        pe[j] = (d & 1) ? cosf(ang) : sinf(ang);
    }
    v.x += pe[0]; v.y += pe[1]; v.z += pe[2]; v.w += pe[3];
    reinterpret_cast<float4*>(x + (size_t)row * DD)[threadIdx.x] = v;
}

// ---------------- fused cos-projection -> bf16 p, optionally transposed p_t ----
template <int WT>
__global__ __launch_bounds__(256) void k_cosp(const float* __restrict__ x,
                                              const float* __restrict__ theta,
                                              short* __restrict__ p,
                                              short* __restrict__ pt) {
    int d0 = blockIdx.x * 64, s0 = blockIdx.y * 64, b = blockIdx.z;
    int t = threadIdx.x;
    int tc = t & 15, tr = t >> 4;
    __shared__ short lt[64][68];
    float4 th = *reinterpret_cast<const float4*>(theta + d0 + tc * 4);
#pragma unroll
    for (int i = 0; i < 4; ++i) {
        int s = tr + 16 * i;
        float4 xv = *reinterpret_cast<const float4*>(
            x + ((size_t)b * SS + s0 + s) * DD + d0 + tc * 4);
        short4 o;
        o.x = f2bf(cosf(xv.x + th.x));
        o.y = f2bf(cosf(xv.y + th.y));
        o.z = f2bf(cosf(xv.z + th.z));
        o.w = f2bf(cosf(xv.w + th.w));
        *reinterpret_cast<short4*>(p + ((size_t)b * SS + s0 + s) * DD + d0 + tc * 4) = o;
        if (WT) {
            lt[tc * 4 + 0][s] = o.x;
            lt[tc * 4 + 1][s] = o.y;
            lt[tc * 4 + 2][s] = o.z;
            lt[tc * 4 + 3][s] = o.w;
        }
    }
    if (WT) {
        __syncthreads();
#pragma unroll
        for (int i = 0; i < 4; ++i) {
            int d = tr + 16 * i;
            short4 v;
            v.x = lt[d][tc * 4 + 0];
            v.y = lt[d][tc * 4 + 1];
            v.z = lt[d][tc * 4 + 2];
            v.w = lt[d][tc * 4 + 3];
            *reinterpret_cast<short4*>(pt + ((size_t)b * DD + d0 + d) * SS + s0 + tc * 4) = v;
        }
    }
}

// ---------------- weight transpose+convert: f32 [K][N] -> bf16 [N][K] ----------
__global__ __launch_bounds__(256) void k_wtrans(const float* __restrict__ W,
                                                short* __restrict__ Wt,
                                                int K, int N) {
    __shared__ float tile[32][33];
    int n0 = blockIdx.x * 32, k0 = blockIdx.y * 32;
    int tx = threadIdx.x & 31, ty = threadIdx.x >> 5;   // 32 x 8
#pragma unroll
    for (int i = 0; i < 4; ++i)
        tile[ty + 8 * i][tx] = W[(size_t)(k0 + ty + 8 * i) * N + n0 + tx];
    __syncthreads();
#pragma unroll
    for (int i = 0; i < 4; ++i)
        Wt[(size_t)(n0 + ty + 8 * i) * K + k0 + tx] = f2bf(tile[tx][ty + 8 * i]);
}

// ---------------- MFMA attention (q=k=v=p), streaming softmax, no max needed ---
__global__ __launch_bounds__(256) void k_attn(const short* __restrict__ p,
                                              const short* __restrict__ pt,
                                              short* __restrict__ aout) {
    int qc = blockIdx.x, h = blockIdx.y, b = blockIdx.z;
    int t = threadIdx.x, w = t >> 6, l = t & 63;
    int lg = l >> 4, lr = l & 15;

    __shared__ __attribute__((aligned(16))) short Kt[128 * 64];   // [k][d] 16KB
    __shared__ __attribute__((aligned(16))) short Vt[64 * 128];   // [d][k] 16KB
    __shared__ __attribute__((aligned(16))) short Pl[4][16 * 136]; // per-wave P [q][k]

    const size_t prow = ((size_t)b * SS + qc * 64 + w * 16 + lr) * DD + h * DK;
    bf16x8 qf0 = *reinterpret_cast<const bf16x8*>(p + prow + lg * 8);
    bf16x8 qf1 = *reinterpret_cast<const bf16x8*>(p + prow + 32 + lg * 8);

    f32x4 acc[4];
#pragma unroll
    for (int dt = 0; dt < 4; ++dt) acc[dt] = (f32x4){0.f, 0.f, 0.f, 0.f};
    float denom = 0.f;

    const short* pK = p + (size_t)b * SS * DD + h * DK;        // + k*DD
    const short* pV = pt + ((size_t)b * DD + h * DK) * SS;     // + d*SS

    short* myP = &Pl[w][0];

    for (int k0 = 0; k0 < SS; k0 += 128) {
        __syncthreads();
#pragma unroll
        for (int i = 0; i < 4; ++i) {
            int c = i * 256 + t;
            int row = c >> 3, sl = c & 7, ssl = sl ^ (row & 7);
            gload_lds16(pK + (size_t)(k0 + row) * DD + ssl * 8,
                        Kt + (size_t)(i * 256 + w * 64) * 8);
        }
#pragma unroll
        for (int i = 0; i < 4; ++i) {
            int c = i * 256 + t;
            int row = c >> 4, sl = c & 15, ssl = sl ^ ((row & 7) * 2);
            gload_lds16(pV + (size_t)row * SS + k0 + ssl * 8,
                        Vt + (size_t)(i * 256 + w * 64) * 8);
        }
        asm volatile("s_waitcnt vmcnt(0)" ::: "memory");
        __syncthreads();

        f32x4 sc[8];
#pragma unroll
        for (int kt = 0; kt < 8; ++kt) {
            int row = kt * 16 + lr;
            bf16x8 ka0 = *reinterpret_cast<const bf16x8*>(Kt + row * 64 + ((lg ^ (row & 7)) * 8));
            bf16x8 ka1 = *reinterpret_cast<const bf16x8*>(Kt + row * 64 + (((lg + 4) ^ (row & 7)) * 8));
            f32x4 z = (f32x4){0.f, 0.f, 0.f, 0.f};
            z = __builtin_amdgcn_mfma_f32_16x16x32_bf16(ka0, qf0, z, 0, 0, 0);
            z = __builtin_amdgcn_mfma_f32_16x16x32_bf16(ka1, qf1, z, 0, 0, 0);
            sc[kt] = z;
        }
#pragma unroll
        for (int kt = 0; kt < 8; ++kt) {
            float e0 = __expf(sc[kt].x * 0.125f);
            float e1 = __expf(sc[kt].y * 0.125f);
            float e2 = __expf(sc[kt].z * 0.125f);
            float e3 = __expf(sc[kt].w * 0.125f);
            denom += (e0 + e1) + (e2 + e3);
            short4 pk;
            pk.x = f2bf(e0); pk.y = f2bf(e1); pk.z = f2bf(e2); pk.w = f2bf(e3);
            *reinterpret_cast<short4*>(myP + lr * 136 + kt * 16 + lg * 4) = pk;
        }
        asm volatile("s_waitcnt lgkmcnt(0)" ::: "memory");
#pragma unroll
        for (int kt2 = 0; kt2 < 4; ++kt2) {
            bf16x8 pb = *reinterpret_cast<const bf16x8*>(myP + lr * 136 + kt2 * 32 + lg * 8);
#pragma unroll
            for (int dt = 0; dt < 4; ++dt) {
                int row = dt * 16 + lr;
                bf16x8 va = *reinterpret_cast<const bf16x8*>(
                    Vt + row * 128 + (((kt2 * 4 + lg) ^ ((row & 7) * 2)) * 8));
                acc[dt] = __builtin_amdgcn_mfma_f32_16x16x32_bf16(va, pb, acc[dt], 0, 0, 0);
            }
        }
    }

    denom += __shfl_xor(denom, 16);
    denom += __shfl_xor(denom, 32);
    float inv = 1.0f / denom;

    size_t orow = ((size_t)b * SS + qc * 64 + w * 16 + lr) * DD + h * DK;
#pragma unroll
    for (int dt = 0; dt < 4; ++dt) {
        short4 o;
        o.x = f2bf(acc[dt].x * inv);
        o.y = f2bf(acc[dt].y * inv);
        o.z = f2bf(acc[dt].z * inv);
        o.w = f2bf(acc[dt].w * inv);
        *reinterpret_cast<short4*>(aout + orow + dt * 16 + lg * 4) = o;
    }
}

// ---------------- bf16 MFMA GEMM: C[M,N] = A[M,K] * W[K,N] + bias ---------------
// 128x128 tile, BK=32, 4 waves 2x2, 4-buffer / 3-deep prefetch, counted vmcnt,
// raw s_barrier (no vmcnt(0) drain in steady state), XCD swizzle.
// grid: 1-D nwg = (N/128)*(M/128), gx = N/128.
template <int RELU, int OUTBF>
__global__ __launch_bounds__(256) void k_mm(const short* __restrict__ A,
                                            const short* __restrict__ Bt,
                                            const float* __restrict__ bias,
                                            void* __restrict__ C,
                                            int N, int K, int gx) {
    __shared__ __attribute__((aligned(16))) short Al[4][128 * 32];
    __shared__ __attribute__((aligned(16))) short Bl[4][128 * 32];
    int t = threadIdx.x, w = t >> 6, l = t & 63;
    int lg = l >> 4, lr = l & 15;
    int wm = w >> 1, wn = w & 1;

    // bijective XCD swizzle: group consecutive logical tiles on one XCD
    int nwg = gridDim.x;
    int bid = blockIdx.x;
    int swz = (bid & 7) * (nwg >> 3) + (bid >> 3);
    int bx = swz % gx, by = swz / gx;
    int row0 = by * 128, col0 = bx * 128;

    f32x4 acc[4][4];
#pragma unroll
    for (int m = 0; m < 4; ++m)
#pragma unroll
        for (int n = 0; n < 4; ++n) acc[m][n] = (f32x4){0.f, 0.f, 0.f, 0.f};

#define STAGE_MM(buf, kk0)                                                      \
    {                                                                           \
        _Pragma("unroll")                                                       \
        for (int i = 0; i < 2; ++i) {                                           \
            int c = i * 256 + t;                                                \
            int row = c >> 2, sl = c & 3, ssl = sl ^ ((row >> 1) & 3);          \
            gload_lds16(A + (size_t)(row0 + row) * K + (kk0) + ssl * 8,         \
                        &Al[buf][0] + (size_t)(i * 256 + w * 64) * 8);          \
            gload_lds16(Bt + (size_t)(col0 + row) * K + (kk0) + ssl * 8,        \
                        &Bl[buf][0] + (size_t)(i * 256 + w * 64) * 8);          \
        }                                                                       \
    }

    const int nk = K >> 5;
    // prologue: 3 tiles in flight (12 loads/thread)
    STAGE_MM(0, 0);
    if (nk > 1) STAGE_MM(1, 32);
    if (nk > 2) STAGE_MM(2, 64);

    for (int kt = 0; kt < nk; ++kt) {
        // tile kt ready when only the (<=2) younger stages remain outstanding
        if (kt + 2 < nk)
            asm volatile("s_waitcnt vmcnt(8)\n\ts_barrier" ::: "memory");
        else if (kt + 1 < nk)
            asm volatile("s_waitcnt vmcnt(4)\n\ts_barrier" ::: "memory");
        else
            asm volatile("s_waitcnt vmcnt(0)\n\ts_barrier" ::: "memory");

        const short* a_ = &Al[kt & 3][0];
        const short* b_ = &Bl[kt & 3][0];
        bf16x8 af[4], bfr[4];
#pragma unroll
        for (int m = 0; m < 4; ++m) {
            int row = wm * 64 + m * 16 + lr;
            af[m] = *reinterpret_cast<const bf16x8*>(a_ + row * 32 + ((lg ^ ((row >> 1) & 3)) * 8));
        }
#pragma unroll
        for (int n = 0; n < 4; ++n) {
            int row = wn * 64 + n * 16 + lr;
            bfr[n] = *reinterpret_cast<const bf16x8*>(b_ + row * 32 + ((lg ^ ((row >> 1) & 3)) * 8));
        }
        // prefetch tile kt+3 into the buffer whose reads completed last iter
        if (kt + 3 < nk) STAGE_MM((kt + 3) & 3, (kt + 3) * 32);

#pragma unroll
        for (int m = 0; m < 4; ++m)
#pragma unroll
            for (int n = 0; n < 4; ++n)
                acc[m][n] = __builtin_amdgcn_mfma_f32_16x16x32_bf16(af[m], bfr[n], acc[m][n], 0, 0, 0);
    }
#undef STAGE_MM

    float bv[4];
#pragma unroll
    for (int n = 0; n < 4; ++n) bv[n] = bias[col0 + wn * 64 + n * 16 + lr];

#pragma unroll
    for (int m = 0; m < 4; ++m) {
#pragma unroll
        for (int n = 0; n < 4; ++n) {
            int col = col0 + wn * 64 + n * 16 + lr;
#pragma unroll
            for (int j = 0; j < 4; ++j) {
                int row = row0 + wm * 64 + m * 16 + lg * 4 + j;
                float v = acc[m][n][j] + bv[n];
                if (RELU) v = fmaxf(v, 0.f);
                if (OUTBF) ((short*)C)[(size_t)row * N + col] = f2bf(v);
                else       ((float*)C)[(size_t)row * N + col] = v;
            }
        }
    }
}

// ------- x = LayerNorm(x + r)*g + b; optionally also p = bf16(cos(x + theta)) ----
template <int COSP>
__global__ __launch_bounds__(128) void k_add_ln(float* __restrict__ x,
                                                const float* __restrict__ rr,
                                                const float* __restrict__ g,
                                                const float* __restrict__ bb,
                                                const float* __restrict__ theta,
                                                short* __restrict__ p) {
    int row = blockIdx.x;
    int t = threadIdx.x;
    float4 v = *reinterpret_cast<const float4*>(x + (size_t)row * DD + t * 4);
    float4 av = *reinterpret_cast<const float4*>(rr + (size_t)row * DD + t * 4);
    v.x += av.x; v.y += av.y; v.z += av.z; v.w += av.w;
    float s = v.x + v.y + v.z + v.w;
    float s2 = v.x * v.x + v.y * v.y + v.z * v.z + v.w * v.w;
#pragma unroll
    for (int off = 32; off > 0; off >>= 1) {
        s += __shfl_down(s, off);
        s2 += __shfl_down(s2, off);
    }
    __shared__ float ls[2], ls2[2];
    if ((t & 63) == 0) { ls[t >> 6] = s; ls2[t >> 6] = s2; }
    __syncthreads();
    float S1 = ls[0] + ls[1];
    float S2 = ls2[0] + ls2[1];
    float mu = S1 * (1.0f / DD);
    float var = S2 * (1.0f / DD) - mu * mu;
    float rstd = rsqrtf(var + 1e-5f);
    float4 gv = *reinterpret_cast<const float4*>(g + t * 4);
    float4 bv = *reinterpret_cast<const float4*>(bb + t * 4);
    float4 o;
    o.x = gv.x * (v.x - mu) * rstd + bv.x;
    o.y = gv.y * (v.y - mu) * rstd + bv.y;
    o.z = gv.z * (v.z - mu) * rstd + bv.z;
    o.w = gv.w * (v.w - mu) * rstd + bv.w;
    *reinterpret_cast<float4*>(x + (size_t)row * DD + t * 4) = o;
    if (COSP) {
        float4 th = *reinterpret_cast<const float4*>(theta + t * 4);
        short4 pk;
        pk.x = f2bf(cosf(o.x + th.x));
        pk.y = f2bf(cosf(o.y + th.y));
        pk.z = f2bf(cosf(o.z + th.z));
        pk.w = f2bf(cosf(o.w + th.w));
        *reinterpret_cast<short4*>(p + (size_t)row * DD + t * 4) = pk;
    }
}

// ---------------- mean-pool stage 1: partial sums over 32-row chunks ------------
__global__ __launch_bounds__(128) void k_pool(const float* __restrict__ x,
                                              float* __restrict__ part) {
    int b = blockIdx.x, c = blockIdx.y;     // 8 x 32
    int t = threadIdx.x;                    // 128 threads x float4
    float4 s = {0.f, 0.f, 0.f, 0.f};
    for (int i = 0; i < 32; ++i) {
        float4 v = reinterpret_cast<const float4*>(
            x + ((size_t)b * SS + c * 32 + i) * DD)[t];
        s.x += v.x; s.y += v.y; s.z += v.z; s.w += v.w;
    }
    reinterpret_cast<float4*>(part + ((size_t)b * 32 + c) * DD)[t] = s;
}

// ---------------- pool stage 2 + classifier ----------------
__global__ __launch_bounds__(512) void k_cls(const float* __restrict__ part,
                                             const float* __restrict__ Wcls,
                                             const float* __restrict__ bcls,
                                             float* __restrict__ out) {
    int b = blockIdx.x;
    int t = threadIdx.x;                    // d = t
    float s = 0.f;
    for (int i = 0; i < 32; ++i) s += part[((size_t)b * 32 + i) * DD + t];
    float pooled = s * (1.0f / SS);
    float acc[NCLS];
#pragma unroll
    for (int c = 0; c < NCLS; ++c) acc[c] = pooled * Wcls[t * NCLS + c];
#pragma unroll
    for (int off = 32; off > 0; off >>= 1)
#pragma unroll
        for (int c = 0; c < NCLS; ++c) acc[c] += __shfl_xor(acc[c], off);
    __shared__ float wp[8][NCLS];
    int w = t >> 6, l = t & 63;
    if (l == 0)
#pragma unroll
        for (int c = 0; c < NCLS; ++c) wp[w][c] = acc[c];
    __syncthreads();
    if (t < NCLS) {
        float o = bcls[t];
#pragma unroll
        for (int i = 0; i < 8; ++i) o += wp[i][t];
        out[b * NCLS + t] = o;
    }
}

extern "C" void kernel_launch(void* const* d_in, const int* in_sizes, int n_in,
                              void* d_out, int out_size, void* d_ws, size_t ws_size,
                              hipStream_t stream) {
    const int* tokens      = (const int*)d_in[0];
    const float* emb       = (const float*)d_in[1];
    const float* theta_att = (const float*)d_in[2];
    const float* Wc        = (const float*)d_in[3];
    const float* bc        = (const float*)d_in[4];
    const float* ln1_g     = (const float*)d_in[5];
    const float* ln1_b     = (const float*)d_in[6];
    const float* theta_ffn = (const float*)d_in[7];
    const float* W1        = (const float*)d_in[8];
    const float* b1        = (const float*)d_in[9];
    const float* W2        = (const float*)d_in[10];
    const float* b2        = (const float*)d_in[11];
    const float* ln2_g     = (const float*)d_in[12];
    const float* ln2_b     = (const float*)d_in[13];
    const float* Wcls      = (const float*)d_in[14];
    const float* bcls      = (const float*)d_in[15];
    float* out = (float*)d_out;

    char* wsb = (char*)d_ws;
    float* x    = (float*)(wsb);                         // 16 MB
    float* t0   = (float*)(wsb + (size_t)16 * 1048576);  // 16 MB
    short* p    = (short*)(wsb + (size_t)32 * 1048576);  // 8 MB
    short* pt   = (short*)(wsb + (size_t)40 * 1048576);  // 8 MB
    short* a    = (short*)(wsb + (size_t)48 * 1048576);  // 8 MB
    short* hh   = (short*)(wsb + (size_t)56 * 1048576);  // 32 MB
    short* Wct  = (short*)(wsb + (size_t)88 * 1048576);  // 0.5 MB
    short* W1t  = (short*)(wsb + (size_t)89 * 1048576);  // 2 MB
    short* W2t  = (short*)(wsb + (size_t)91 * 1048576);  // 2 MB
    float* part = (float*)(wsb + (size_t)94 * 1048576);  // 0.5 MB

    k_embed_pe<<<ROWS, 128, 0, stream>>>(tokens, emb, x);

    for (int l = 0; l < NLAYERS; ++l) {
        k_wtrans<<<dim3(DD / 32, DD / 32), 256, 0, stream>>>(Wc + (size_t)l * DD * DD, Wct, DD, DD);
        k_wtrans<<<dim3(FF / 32, DD / 32), 256, 0, stream>>>(W1 + (size_t)l * DD * FF, W1t, DD, FF);
        k_wtrans<<<dim3(DD / 32, FF / 32), 256, 0, stream>>>(W2 + (size_t)l * FF * DD, W2t, FF, DD);

        // --- MHA ---
        k_cosp<1><<<dim3(DD / 64, SS / 64, BB), 256, 0, stream>>>(x, theta_att + l * DD, p, pt);
        k_attn<<<dim3(SS / 64, HH, BB), 256, 0, stream>>>(p, pt, a);
        k_mm<0, 0><<<(DD / 128) * (ROWS / 128), 256, 0, stream>>>(
            a, Wct, bc + l * DD, t0, DD, DD, DD / 128);
        // ln1 fused with FFN cos-projection
        k_add_ln<1><<<ROWS, 128, 0, stream>>>(x, t0, ln1_g + l * DD, ln1_b + l * DD,
                                              theta_ffn + l * DD, p);
        // --- FFN ---
        k_mm<1, 1><<<(FF / 128) * (ROWS / 128), 256, 0, stream>>>(
            p, W1t, b1 + l * FF, hh, FF, DD, FF / 128);
        k_mm<0, 0><<<(DD / 128) * (ROWS / 128), 256, 0, stream>>>(
            hh, W2t, b2 + l * DD, t0, DD, FF, DD / 128);
        k_add_ln<0><<<ROWS, 128, 0, stream>>>(x, t0, ln2_g + l * DD, ln2_b + l * DD,
                                              (const float*)nullptr, (short*)nullptr);
    }

    k_pool<<<dim3(BB, 32), 128, 0, stream>>>(x, part);
    k_cls<<<BB, 512, 0, stream>>>(part, Wcls, bcls, out);
}

// Round 6
// 418.787 us; speedup vs baseline: 6.5410x; 1.0191x over previous
//
#include <hip/hip_runtime.h>
#include <math.h>

#define BB 8
#define SS 1024
#define DD 512
#define HH 8
#define DK 64
#define FF 2048
#define NCLS 10
#define ROWS (BB*SS)   // 8192
#define NLAYERS 2

typedef short bf16x8 __attribute__((ext_vector_type(8)));
typedef float f32x4 __attribute__((ext_vector_type(4)));

__device__ inline short f2bf(float f) {
    unsigned u = __float_as_uint(f);
    u += 0x7FFF + ((u >> 16) & 1);          // round-to-nearest-even
    return (short)(u >> 16);
}

__device__ inline void gload_lds16(const void* g, void* l) {
    __builtin_amdgcn_global_load_lds((const __attribute__((address_space(1))) void*)g,
                                     (__attribute__((address_space(3))) void*)l, 16, 0, 0);
}

// ---------------- embedding + sinusoidal positional encoding ----------------
__global__ __launch_bounds__(128) void k_embed_pe(const int* __restrict__ tokens,
                                                  const float* __restrict__ emb,
                                                  float* __restrict__ x) {
    int row = blockIdx.x;            // b*S + s
    int s = row & (SS - 1);
    int tok = tokens[row];
    const float4* e = reinterpret_cast<const float4*>(emb + (size_t)tok * DD);
    float4 v = e[threadIdx.x];
    float pe[4];
#pragma unroll
    for (int j = 0; j < 4; ++j) {
        int d = threadIdx.x * 4 + j;
        int jj = d >> 1;
        float inv = expf(-((float)(2 * jj) / (float)DD) * 9.210340371976184f);
        float ang = (float)s * inv;
        pe[j] = (d & 1) ? cosf(ang) : sinf(ang);
    }
    v.x += pe[0]; v.y += pe[1]; v.z += pe[2]; v.w += pe[3];
    reinterpret_cast<float4*>(x + (size_t)row * DD)[threadIdx.x] = v;
}

// ---------------- fused cos-projection -> bf16 p, optionally transposed p_t ----
template <int WT>
__global__ __launch_bounds__(256) void k_cosp(const float* __restrict__ x,
                                              const float* __restrict__ theta,
                                              short* __restrict__ p,
                                              short* __restrict__ pt) {
    int d0 = blockIdx.x * 64, s0 = blockIdx.y * 64, b = blockIdx.z;
    int t = threadIdx.x;
    int tc = t & 15, tr = t >> 4;
    __shared__ short lt[64][68];
    float4 th = *reinterpret_cast<const float4*>(theta + d0 + tc * 4);
#pragma unroll
    for (int i = 0; i < 4; ++i) {
        int s = tr + 16 * i;
        float4 xv = *reinterpret_cast<const float4*>(
            x + ((size_t)b * SS + s0 + s) * DD + d0 + tc * 4);
        short4 o;
        o.x = f2bf(cosf(xv.x + th.x));
        o.y = f2bf(cosf(xv.y + th.y));
        o.z = f2bf(cosf(xv.z + th.z));
        o.w = f2bf(cosf(xv.w + th.w));
        *reinterpret_cast<short4*>(p + ((size_t)b * SS + s0 + s) * DD + d0 + tc * 4) = o;
        if (WT) {
            lt[tc * 4 + 0][s] = o.x;
            lt[tc * 4 + 1][s] = o.y;
            lt[tc * 4 + 2][s] = o.z;
            lt[tc * 4 + 3][s] = o.w;
        }
    }
    if (WT) {
        __syncthreads();
#pragma unroll
        for (int i = 0; i < 4; ++i) {
            int d = tr + 16 * i;
            short4 v;
            v.x = lt[d][tc * 4 + 0];
            v.y = lt[d][tc * 4 + 1];
            v.z = lt[d][tc * 4 + 2];
            v.w = lt[d][tc * 4 + 3];
            *reinterpret_cast<short4*>(pt + ((size_t)b * DD + d0 + d) * SS + s0 + tc * 4) = v;
        }
    }
}

// ---------------- weight transpose+convert: f32 [K][N] -> bf16 [N][K] ----------
__global__ __launch_bounds__(256) void k_wtrans(const float* __restrict__ W,
                                                short* __restrict__ Wt,
                                                int K, int N) {
    __shared__ float tile[32][33];
    int n0 = blockIdx.x * 32, k0 = blockIdx.y * 32;
    int tx = threadIdx.x & 31, ty = threadIdx.x >> 5;   // 32 x 8
#pragma unroll
    for (int i = 0; i < 4; ++i)
        tile[ty + 8 * i][tx] = W[(size_t)(k0 + ty + 8 * i) * N + n0 + tx];
    __syncthreads();
#pragma unroll
    for (int i = 0; i < 4; ++i)
        Wt[(size_t)(n0 + ty + 8 * i) * K + k0 + tx] = f2bf(tile[tx][ty + 8 * i]);
}

// ---------------- MFMA attention (q=k=v=p), streaming softmax, no max needed ---
// |score| <= 8 -> plain running-sum softmax.  QBLK=128 q rows/block (2x16 per
// wave), KVBLK=64, 3-buffer pipelined staging with counted vmcnt (T3/T4).
// Grid 512 = qc*64 + (b*8+h): all 8 q-blocks of one (b,h) land on XCD (b*8+h)&7
// so each XCD caches only 8 heads' K/V (2 MB) in its L2.
#define KVB 64
#define NT (SS / KVB)   // 16
__global__ __launch_bounds__(256) void k_attn(const short* __restrict__ p,
                                              const short* __restrict__ pt,
                                              short* __restrict__ aout) {
    int bid = blockIdx.x;
    int qc = bid >> 6, bh = bid & 63;
    int b = bh >> 3, h = bh & 7;
    int t = threadIdx.x, w = t >> 6, l = t & 63;
    int lg = l >> 4, lr = l & 15;

    __shared__ __attribute__((aligned(16))) short Kt[3][KVB * 64];  // 24 KB [k][d]
    __shared__ __attribute__((aligned(16))) short Vt[3][64 * KVB];  // 24 KB [d][k]
    __shared__ __attribute__((aligned(16))) short Pl[4][16 * 72];   // 18 KB per-wave P

    // Q B-frags for both 16-row subtiles
    bf16x8 qf[2][2];
#pragma unroll
    for (int s = 0; s < 2; ++s) {
        size_t prow = ((size_t)b * SS + qc * 128 + w * 32 + s * 16 + lr) * DD + h * DK;
        qf[s][0] = *reinterpret_cast<const bf16x8*>(p + prow + lg * 8);
        qf[s][1] = *reinterpret_cast<const bf16x8*>(p + prow + 32 + lg * 8);
    }

    f32x4 acc[2][4];
#pragma unroll
    for (int s = 0; s < 2; ++s)
#pragma unroll
        for (int dt = 0; dt < 4; ++dt) acc[s][dt] = (f32x4){0.f, 0.f, 0.f, 0.f};
    float denom[2] = {0.f, 0.f};

    const short* pK = p + (size_t)b * SS * DD + h * DK;        // + k*DD
    const short* pV = pt + ((size_t)b * DD + h * DK) * SS;     // + d*SS
    short* myP = &Pl[w][0];

#define STAGE_ATT(bi, kk0)                                                      \
    {                                                                           \
        _Pragma("unroll")                                                       \
        for (int i = 0; i < 2; ++i) {                                           \
            int c = i * 256 + t;                                                \
            int row = c >> 3, sl = c & 7, ssl = sl ^ (row & 7);                 \
            gload_lds16(pK + (size_t)((kk0) + row) * DD + ssl * 8,              \
                        &Kt[bi][0] + (size_t)(i * 256 + w * 64) * 8);           \
            gload_lds16(pV + (size_t)row * SS + (kk0) + ssl * 8,                \
                        &Vt[bi][0] + (size_t)(i * 256 + w * 64) * 8);           \
        }                                                                       \
    }

    // prologue: tiles 0 and 1 in flight (8 loads/thread)
    STAGE_ATT(0, 0);
    STAGE_ATT(1, KVB);

    for (int kt3 = 0; kt3 < NT; ++kt3) {
        // tile kt3 ready when at most tile kt3+1's 4 loads remain outstanding
        if (kt3 + 1 < NT)
            asm volatile("s_waitcnt vmcnt(4)\n\ts_barrier" ::: "memory");
        else
            asm volatile("s_waitcnt vmcnt(0)\n\ts_barrier" ::: "memory");
        // stage tile kt3+2 (its buffer held kt3-1; all waves are past it now)
        if (kt3 + 2 < NT) STAGE_ATT((kt3 + 2) % 3, (kt3 + 2) * KVB);

        const short* kb = &Kt[kt3 % 3][0];
        const short* vb = &Vt[kt3 % 3][0];

#pragma unroll
        for (int s = 0; s < 2; ++s) {
            // QK^T: S^T[k,q] per 16-k subtile
            f32x4 sc[4];
            __builtin_amdgcn_s_setprio(1);
#pragma unroll
            for (int kt = 0; kt < 4; ++kt) {
                int row = kt * 16 + lr;
                bf16x8 ka0 = *reinterpret_cast<const bf16x8*>(kb + row * 64 + ((lg ^ (row & 7)) * 8));
                bf16x8 ka1 = *reinterpret_cast<const bf16x8*>(kb + row * 64 + (((lg + 4) ^ (row & 7)) * 8));
                f32x4 z = (f32x4){0.f, 0.f, 0.f, 0.f};
                z = __builtin_amdgcn_mfma_f32_16x16x32_bf16(ka0, qf[s][0], z, 0, 0, 0);
                z = __builtin_amdgcn_mfma_f32_16x16x32_bf16(ka1, qf[s][1], z, 0, 0, 0);
                sc[kt] = z;
            }
            __builtin_amdgcn_s_setprio(0);
            // exp (no max subtraction), accumulate denom, pack to per-wave P LDS
#pragma unroll
            for (int kt = 0; kt < 4; ++kt) {
                float e0 = __expf(sc[kt].x * 0.125f);
                float e1 = __expf(sc[kt].y * 0.125f);
                float e2 = __expf(sc[kt].z * 0.125f);
                float e3 = __expf(sc[kt].w * 0.125f);
                denom[s] += (e0 + e1) + (e2 + e3);
                short4 pk;
                pk.x = f2bf(e0); pk.y = f2bf(e1); pk.z = f2bf(e2); pk.w = f2bf(e3);
                *reinterpret_cast<short4*>(myP + lr * 72 + kt * 16 + lg * 4) = pk;
            }
            asm volatile("s_waitcnt lgkmcnt(0)" ::: "memory");
            // PV: O^T[d,q] += V^T[d,k32] * P^T[k32,q]
            __builtin_amdgcn_s_setprio(1);
#pragma unroll
            for (int kt2 = 0; kt2 < 2; ++kt2) {
                bf16x8 pb = *reinterpret_cast<const bf16x8*>(myP + lr * 72 + kt2 * 32 + lg * 8);
#pragma unroll
                for (int dt = 0; dt < 4; ++dt) {
                    int row = dt * 16 + lr;
                    bf16x8 va = *reinterpret_cast<const bf16x8*>(
                        vb + row * 64 + (((kt2 * 4 + lg) ^ (row & 7)) * 8));
                    acc[s][dt] = __builtin_amdgcn_mfma_f32_16x16x32_bf16(va, pb, acc[s][dt], 0, 0, 0);
                }
            }
            __builtin_amdgcn_s_setprio(0);
        }
    }
#undef STAGE_ATT

#pragma unroll
    for (int s = 0; s < 2; ++s) {
        float d2 = denom[s];
        d2 += __shfl_xor(d2, 16);
        d2 += __shfl_xor(d2, 32);
        float inv = 1.0f / d2;
        size_t orow = ((size_t)b * SS + qc * 128 + w * 32 + s * 16 + lr) * DD + h * DK;
#pragma unroll
        for (int dt = 0; dt < 4; ++dt) {
            short4 o;
            o.x = f2bf(acc[s][dt].x * inv);
            o.y = f2bf(acc[s][dt].y * inv);
            o.z = f2bf(acc[s][dt].z * inv);
            o.w = f2bf(acc[s][dt].w * inv);
            *reinterpret_cast<short4*>(aout + orow + dt * 16 + lg * 4) = o;
        }
    }
}

// ---------------- bf16 MFMA GEMM: C[M,N] = A[M,K] * W[K,N] + bias ---------------
// 128x128 tile, BK=32, 4 waves 2x2, 4-buffer / 3-deep prefetch, counted vmcnt,
// raw s_barrier (no vmcnt(0) drain in steady state), XCD swizzle.
// grid: 1-D nwg = (N/128)*(M/128), gx = N/128.
template <int RELU, int OUTBF>
__global__ __launch_bounds__(256) void k_mm(const short* __restrict__ A,
                                            const short* __restrict__ Bt,
                                            const float* __restrict__ bias,
                                            void* __restrict__ C,
                                            int N, int K, int gx) {
    __shared__ __attribute__((aligned(16))) short Al[4][128 * 32];
    __shared__ __attribute__((aligned(16))) short Bl[4][128 * 32];
    int t = threadIdx.x, w = t >> 6, l = t & 63;
    int lg = l >> 4, lr = l & 15;
    int wm = w >> 1, wn = w & 1;

    // bijective XCD swizzle: group consecutive logical tiles on one XCD
    int nwg = gridDim.x;
    int bid = blockIdx.x;
    int swz = (bid & 7) * (nwg >> 3) + (bid >> 3);
    int bx = swz % gx, by = swz / gx;
    int row0 = by * 128, col0 = bx * 128;

    f32x4 acc[4][4];
#pragma unroll
    for (int m = 0; m < 4; ++m)
#pragma unroll
        for (int n = 0; n < 4; ++n) acc[m][n] = (f32x4){0.f, 0.f, 0.f, 0.f};

#define STAGE_MM(buf, kk0)                                                      \
    {                                                                           \
        _Pragma("unroll")                                                       \
        for (int i = 0; i < 2; ++i) {                                           \
            int c = i * 256 + t;                                                \
            int row = c >> 2, sl = c & 3, ssl = sl ^ ((row >> 1) & 3);          \
            gload_lds16(A + (size_t)(row0 + row) * K + (kk0) + ssl * 8,         \
                        &Al[buf][0] + (size_t)(i * 256 + w * 64) * 8);          \
            gload_lds16(Bt + (size_t)(col0 + row) * K + (kk0) + ssl * 8,        \
                        &Bl[buf][0] + (size_t)(i * 256 + w * 64) * 8);          \
        }                                                                       \
    }

    const int nk = K >> 5;
    // prologue: 3 tiles in flight (12 loads/thread)
    STAGE_MM(0, 0);
    if (nk > 1) STAGE_MM(1, 32);
    if (nk > 2) STAGE_MM(2, 64);

    for (int kt = 0; kt < nk; ++kt) {
        // tile kt ready when only the (<=2) younger stages remain outstanding
        if (kt + 2 < nk)
            asm volatile("s_waitcnt vmcnt(8)\n\ts_barrier" ::: "memory");
        else if (kt + 1 < nk)
            asm volatile("s_waitcnt vmcnt(4)\n\ts_barrier" ::: "memory");
        else
            asm volatile("s_waitcnt vmcnt(0)\n\ts_barrier" ::: "memory");

        const short* a_ = &Al[kt & 3][0];
        const short* b_ = &Bl[kt & 3][0];
        bf16x8 af[4], bfr[4];
#pragma unroll
        for (int m = 0; m < 4; ++m) {
            int row = wm * 64 + m * 16 + lr;
            af[m] = *reinterpret_cast<const bf16x8*>(a_ + row * 32 + ((lg ^ ((row >> 1) & 3)) * 8));
        }
#pragma unroll
        for (int n = 0; n < 4; ++n) {
            int row = wn * 64 + n * 16 + lr;
            bfr[n] = *reinterpret_cast<const bf16x8*>(b_ + row * 32 + ((lg ^ ((row >> 1) & 3)) * 8));
        }
        // prefetch tile kt+3 into the buffer whose reads completed last iter
        if (kt + 3 < nk) STAGE_MM((kt + 3) & 3, (kt + 3) * 32);

#pragma unroll
        for (int m = 0; m < 4; ++m)
#pragma unroll
            for (int n = 0; n < 4; ++n)
                acc[m][n] = __builtin_amdgcn_mfma_f32_16x16x32_bf16(af[m], bfr[n], acc[m][n], 0, 0, 0);
    }
#undef STAGE_MM

    float bv[4];
#pragma unroll
    for (int n = 0; n < 4; ++n) bv[n] = bias[col0 + wn * 64 + n * 16 + lr];

#pragma unroll
    for (int m = 0; m < 4; ++m) {
#pragma unroll
        for (int n = 0; n < 4; ++n) {
            int col = col0 + wn * 64 + n * 16 + lr;
#pragma unroll
            for (int j = 0; j < 4; ++j) {
                int row = row0 + wm * 64 + m * 16 + lg * 4 + j;
                float v = acc[m][n][j] + bv[n];
                if (RELU) v = fmaxf(v, 0.f);
                if (OUTBF) ((short*)C)[(size_t)row * N + col] = f2bf(v);
                else       ((float*)C)[(size_t)row * N + col] = v;
            }
        }
    }
}

// ------- x = LayerNorm(x + r)*g + b; optionally also p = bf16(cos(x + theta)) ----
template <int COSP>
__global__ __launch_bounds__(128) void k_add_ln(float* __restrict__ x,
                                                const float* __restrict__ rr,
                                                const float* __restrict__ g,
                                                const float* __restrict__ bb,
                                                const float* __restrict__ theta,
                                                short* __restrict__ p) {
    int row = blockIdx.x;
    int t = threadIdx.x;
    float4 v = *reinterpret_cast<const float4*>(x + (size_t)row * DD + t * 4);
    float4 av = *reinterpret_cast<const float4*>(rr + (size_t)row * DD + t * 4);
    v.x += av.x; v.y += av.y; v.z += av.z; v.w += av.w;
    float s = v.x + v.y + v.z + v.w;
    float s2 = v.x * v.x + v.y * v.y + v.z * v.z + v.w * v.w;
#pragma unroll
    for (int off = 32; off > 0; off >>= 1) {
        s += __shfl_down(s, off);
        s2 += __shfl_down(s2, off);
    }
    __shared__ float ls[2], ls2[2];
    if ((t & 63) == 0) { ls[t >> 6] = s; ls2[t >> 6] = s2; }
    __syncthreads();
    float S1 = ls[0] + ls[1];
    float S2 = ls2[0] + ls2[1];
    float mu = S1 * (1.0f / DD);
    float var = S2 * (1.0f / DD) - mu * mu;
    float rstd = rsqrtf(var + 1e-5f);
    float4 gv = *reinterpret_cast<const float4*>(g + t * 4);
    float4 bv = *reinterpret_cast<const float4*>(bb + t * 4);
    float4 o;
    o.x = gv.x * (v.x - mu) * rstd + bv.x;
    o.y = gv.y * (v.y - mu) * rstd + bv.y;
    o.z = gv.z * (v.z - mu) * rstd + bv.z;
    o.w = gv.w * (v.w - mu) * rstd + bv.w;
    *reinterpret_cast<float4*>(x + (size_t)row * DD + t * 4) = o;
    if (COSP) {
        float4 th = *reinterpret_cast<const float4*>(theta + t * 4);
        short4 pk;
        pk.x = f2bf(cosf(o.x + th.x));
        pk.y = f2bf(cosf(o.y + th.y));
        pk.z = f2bf(cosf(o.z + th.z));
        pk.w = f2bf(cosf(o.w + th.w));
        *reinterpret_cast<short4*>(p + (size_t)row * DD + t * 4) = pk;
    }
}

// ---------------- mean-pool stage 1: partial sums over 32-row chunks ------------
__global__ __launch_bounds__(128) void k_pool(const float* __restrict__ x,
                                              float* __restrict__ part) {
    int b = blockIdx.x, c = blockIdx.y;     // 8 x 32
    int t = threadIdx.x;                    // 128 threads x float4
    float4 s = {0.f, 0.f, 0.f, 0.f};
    for (int i = 0; i < 32; ++i) {
        float4 v = reinterpret_cast<const float4*>(
            x + ((size_t)b * SS + c * 32 + i) * DD)[t];
        s.x += v.x; s.y += v.y; s.z += v.z; s.w += v.w;
    }
    reinterpret_cast<float4*>(part + ((size_t)b * 32 + c) * DD)[t] = s;
}

// ---------------- pool stage 2 + classifier ----------------
__global__ __launch_bounds__(512) void k_cls(const float* __restrict__ part,
                                             const float* __restrict__ Wcls,
                                             const float* __restrict__ bcls,
                                             float* __restrict__ out) {
    int b = blockIdx.x;
    int t = threadIdx.x;                    // d = t
    float s = 0.f;
    for (int i = 0; i < 32; ++i) s += part[((size_t)b * 32 + i) * DD + t];
    float pooled = s * (1.0f / SS);
    float acc[NCLS];
#pragma unroll
    for (int c = 0; c < NCLS; ++c) acc[c] = pooled * Wcls[t * NCLS + c];
#pragma unroll
    for (int off = 32; off > 0; off >>= 1)
#pragma unroll
        for (int c = 0; c < NCLS; ++c) acc[c] += __shfl_xor(acc[c], off);
    __shared__ float wp[8][NCLS];
    int w = t >> 6, l = t & 63;
    if (l == 0)
#pragma unroll
        for (int c = 0; c < NCLS; ++c) wp[w][c] = acc[c];
    __syncthreads();
    if (t < NCLS) {
        float o = bcls[t];
#pragma unroll
        for (int i = 0; i < 8; ++i) o += wp[i][t];
        out[b * NCLS + t] = o;
    }
}

extern "C" void kernel_launch(void* const* d_in, const int* in_sizes, int n_in,
                              void* d_out, int out_size, void* d_ws, size_t ws_size,
                              hipStream_t stream) {
    const int* tokens      = (const int*)d_in[0];
    const float* emb       = (const float*)d_in[1];
    const float* theta_att = (const float*)d_in[2];
    const float* Wc        = (const float*)d_in[3];
    const float* bc        = (const float*)d_in[4];
    const float* ln1_g     = (const float*)d_in[5];
    const float* ln1_b     = (const float*)d_in[6];
    const float* theta_ffn = (const float*)d_in[7];
    const float* W1        = (const float*)d_in[8];
    const float* b1        = (const float*)d_in[9];
    const float* W2        = (const float*)d_in[10];
    const float* b2        = (const float*)d_in[11];
    const float* ln2_g     = (const float*)d_in[12];
    const float* ln2_b     = (const float*)d_in[13];
    const float* Wcls      = (const float*)d_in[14];
    const float* bcls      = (const float*)d_in[15];
    float* out = (float*)d_out;

    char* wsb = (char*)d_ws;
    float* x    = (float*)(wsb);                         // 16 MB
    float* t0   = (float*)(wsb + (size_t)16 * 1048576);  // 16 MB
    short* p    = (short*)(wsb + (size_t)32 * 1048576);  // 8 MB
    short* pt   = (short*)(wsb + (size_t)40 * 1048576);  // 8 MB
    short* a    = (short*)(wsb + (size_t)48 * 1048576);  // 8 MB
    short* hh   = (short*)(wsb + (size_t)56 * 1048576);  // 32 MB
    short* Wct  = (short*)(wsb + (size_t)88 * 1048576);  // 0.5 MB
    short* W1t  = (short*)(wsb + (size_t)89 * 1048576);  // 2 MB
    short* W2t  = (short*)(wsb + (size_t)91 * 1048576);  // 2 MB
    float* part = (float*)(wsb + (size_t)94 * 1048576);  // 0.5 MB

    k_embed_pe<<<ROWS, 128, 0, stream>>>(tokens, emb, x);

    for (int l = 0; l < NLAYERS; ++l) {
        k_wtrans<<<dim3(DD / 32, DD / 32), 256, 0, stream>>>(Wc + (size_t)l * DD * DD, Wct, DD, DD);
        k_wtrans<<<dim3(FF / 32, DD / 32), 256, 0, stream>>>(W1 + (size_t)l * DD * FF, W1t, DD, FF);
        k_wtrans<<<dim3(DD / 32, FF / 32), 256, 0, stream>>>(W2 + (size_t)l * FF * DD, W2t, FF, DD);

        // --- MHA ---
        k_cosp<1><<<dim3(DD / 64, SS / 64, BB), 256, 0, stream>>>(x, theta_att + l * DD, p, pt);
        k_attn<<<(SS / 128) * BB * HH, 256, 0, stream>>>(p, pt, a);
        k_mm<0, 0><<<(DD / 128) * (ROWS / 128), 256, 0, stream>>>(
            a, Wct, bc + l * DD, t0, DD, DD, DD / 128);
        // ln1 fused with FFN cos-projection
        k_add_ln<1><<<ROWS, 128, 0, stream>>>(x, t0, ln1_g + l * DD, ln1_b + l * DD,
                                              theta_ffn + l * DD, p);
        // --- FFN ---
        k_mm<1, 1><<<(FF / 128) * (ROWS / 128), 256, 0, stream>>>(
            p, W1t, b1 + l * FF, hh, FF, DD, FF / 128);
        k_mm<0, 0><<<(DD / 128) * (ROWS / 128), 256, 0, stream>>>(
            hh, W2t, b2 + l * DD, t0, DD, FF, DD / 128);
        k_add_ln<0><<<ROWS, 128, 0, stream>>>(x, t0, ln2_g + l * DD, ln2_b + l * DD,
                                              (const float*)nullptr, (short*)nullptr);
    }

    k_pool<<<dim3(BB, 32), 128, 0, stream>>>(x, part);
    k_cls<<<BB, 512, 0, stream>>>(part, Wcls, bcls, out);
}